// Round 1
// baseline (1692.504 us; speedup 1.0000x reference)
//
#include <hip/hip_runtime.h>
#include <hip/hip_bf16.h>
#include <math.h>

// Problem constants (hardcoded from reference)
constexpr int B_ = 4, N_ = 384, H_ = 256, NH_ = 8, DD_ = 32, L_ = 4;
constexpr int M_ = B_ * N_;          // 1536 node rows
constexpr float CUT = 5.0f;
constexpr float PI_ = 3.14159265358979323846f;
constexpr float INVSC = 0.17677669529663687f;  // 1/sqrt(32)
constexpr int TBL_N = 4096;                     // intervals; values at 0..4096, diag at 4097
constexpr int TBL_STRIDE = 4098;
constexpr float NEGV = -3.0e38f;

__device__ __forceinline__ float wave_sum(float v) {
#pragma unroll
  for (int s = 1; s < 64; s <<= 1) v += __shfl_xor(v, s);
  return v;
}
__device__ __forceinline__ float wave_max(float v) {
#pragma unroll
  for (int s = 1; s < 64; s <<= 1) v = fmaxf(v, __shfl_xor(v, s));
  return v;
}

// ---------------- embed: x = emb[idx] * maskb ----------------
__global__ __launch_bounds__(256) void embed_k(const int* __restrict__ idx,
                                               const float* __restrict__ mask,
                                               const float* __restrict__ emb,
                                               float* __restrict__ X) {
  int e = blockIdx.x * 256 + threadIdx.x;   // < M_*H_
  int mrow = e >> 8, c = e & 255;
  float mb = mask[mrow] > 0.f ? 1.f : 0.f;
  X[e] = emb[idx[mrow] * H_ + c] * mb;
}

// ---------------- dist: masked distances ----------------
__global__ __launch_bounds__(256) void dist_k(const float* __restrict__ pos,
                                              const float* __restrict__ mask,
                                              float* __restrict__ distm) {
  int e = blockIdx.x * 256 + threadIdx.x;   // < B*N*N
  int j = e % N_;
  int t = e / N_;
  int i = t % N_;
  int b = t / N_;
  float mi = mask[b * N_ + i], mj = mask[b * N_ + j];
  const float* pi = pos + (size_t)(b * N_ + i) * 3;
  const float* pj = pos + (size_t)(b * N_ + j) * 3;
  float dx = pi[0] - pj[0] + 1e-9f;
  float dy = pi[1] - pj[1] + 1e-9f;
  float dz = pi[2] - pj[2] + 1e-9f;
  float d = sqrtf(dx * dx + dy * dy + dz * dz);
  distm[e] = (mi > 0.f && mj > 0.f) ? d : 1e30f;
}

// ---------------- bias table: g_{l,h}(d) ----------------
// grid = L_*4098 blocks, 256 threads. t in [0,4096] -> d = t*5/4096 ; t==4097 -> diagonal dist
__global__ __launch_bounds__(256) void table_k(const float* __restrict__ rb_w1,
                                               const float* __restrict__ rb_b1,
                                               const float* __restrict__ rb_w2,
                                               const float* __restrict__ rb_b2,
                                               float* __restrict__ tbl) {
  int bid = blockIdx.x;
  int l = bid / TBL_STRIDE;
  int t = bid % TBL_STRIDE;
  int tid = threadIdx.x;
  float d = (t <= TBL_N) ? (t * (CUT / (float)TBL_N)) : 1.7320508075688772e-9f;
  __shared__ float sf[DD_];
  if (tid < DD_) {
    float ang = PI_ * (tid + 1) * d * (1.f / CUT);
    sf[tid] = sinf(ang) / (d + 1e-6f);   // (d<=CUT) always true here
  }
  __syncthreads();
  int h = tid;
  const float* w1 = rb_w1 + (size_t)l * DD_ * H_;
  float pre = rb_b1[l * H_ + h];
#pragma unroll
  for (int k = 0; k < DD_; k++) pre += sf[k] * w1[k * H_ + h];
  float hb = pre / (1.f + expf(-pre));   // silu
  const float* w2 = rb_w2 + (size_t)l * H_ * NH_ + h * NH_;
  float part[NH_];
#pragma unroll
  for (int o = 0; o < NH_; o++) part[o] = hb * w2[o];
#pragma unroll
  for (int o = 0; o < NH_; o++) part[o] = wave_sum(part[o]);
  __shared__ float sacc[4][NH_];
  int wave = tid >> 6, lane = tid & 63;
  if (lane == 0) {
#pragma unroll
    for (int o = 0; o < NH_; o++) sacc[wave][o] = part[o];
  }
  __syncthreads();
  if (tid < NH_) {
    float r = sacc[0][tid] + sacc[1][tid] + sacc[2][tid] + sacc[3][tid] + rb_b2[l * NH_ + tid];
    tbl[(size_t)(l * NH_ + tid) * TBL_STRIDE + t] = r;
  }
}

// ---------------- LayerNorm (row of 256), one wave per row ----------------
__global__ __launch_bounds__(256) void ln_k(const float* __restrict__ X,
                                            const float* __restrict__ g,
                                            const float* __restrict__ bta,
                                            float* __restrict__ O) {
  int wave = threadIdx.x >> 6, lane = threadIdx.x & 63;
  int row = blockIdx.x * 4 + wave;
  const float* xr = X + (size_t)row * H_;
  float4 v = *(const float4*)(xr + lane * 4);
  float s = v.x + v.y + v.z + v.w;
  s = wave_sum(s);
  float m = s * (1.f / H_);
  float dx = v.x - m, dy = v.y - m, dz = v.z - m, dw = v.w - m;
  float vs = dx * dx + dy * dy + dz * dz + dw * dw;
  vs = wave_sum(vs);
  float rs = rsqrtf(vs * (1.f / H_) + 1e-5f);
  float4 gg = *(const float4*)(g + lane * 4);
  float4 bb = *(const float4*)(bta + lane * 4);
  float4 o;
  o.x = dx * rs * gg.x + bb.x;
  o.y = dy * rs * gg.y + bb.y;
  o.z = dz * rs * gg.z + bb.z;
  o.w = dw * rs * gg.w + bb.w;
  *(float4*)(O + (size_t)row * H_ + lane * 4) = o;
}

// ---------------- generic tiled fp32 GEMM: C[M,Nc] = act(A[M,K]@W[K,Nc] + bias) (+resid) ----
// BM=BN=64, BK=16, 256 threads, 4x4 register tile. M fixed = 1536.
template <int ACT, bool RES>
__global__ __launch_bounds__(256) void gemm_k(const float* __restrict__ A,
                                              const float* __restrict__ W,
                                              const float* __restrict__ bias,
                                              const float* __restrict__ resid,
                                              float* __restrict__ C, int K, int Nc) {
  __shared__ float As[16][68];
  __shared__ float Bs[16][64];
  const int n0 = blockIdx.x * 64, m0 = blockIdx.y * 64;
  const int tid = threadIdx.x;
  const int trow = tid >> 4, tcol = tid & 15;
  const int arow = tid >> 2, akq = (tid & 3) << 2;
  const int brow = tid >> 4, bc = (tid & 15) << 2;
  float acc[4][4] = {};
  for (int k0 = 0; k0 < K; k0 += 16) {
    float4 av = *(const float4*)(A + (size_t)(m0 + arow) * K + k0 + akq);
    As[akq + 0][arow] = av.x;
    As[akq + 1][arow] = av.y;
    As[akq + 2][arow] = av.z;
    As[akq + 3][arow] = av.w;
    *(float4*)(&Bs[brow][bc]) = *(const float4*)(W + (size_t)(k0 + brow) * Nc + n0 + bc);
    __syncthreads();
#pragma unroll
    for (int kk = 0; kk < 16; kk++) {
      float4 a = *(const float4*)(&As[kk][trow << 2]);
      float4 b = *(const float4*)(&Bs[kk][tcol << 2]);
      float aa[4] = {a.x, a.y, a.z, a.w};
      float bb[4] = {b.x, b.y, b.z, b.w};
#pragma unroll
      for (int i = 0; i < 4; i++)
#pragma unroll
        for (int j = 0; j < 4; j++) acc[i][j] += aa[i] * bb[j];
    }
    __syncthreads();
  }
#pragma unroll
  for (int i = 0; i < 4; i++) {
    int row = m0 + (trow << 2) + i;
#pragma unroll
    for (int j = 0; j < 4; j++) {
      int col = n0 + (tcol << 2) + j;
      float v = acc[i][j] + bias[col];
      if (ACT == 1) v = v / (1.f + __expf(-v));                       // silu
      if (ACT == 2) v = 0.5f * v * (1.f + erff(v * 0.70710678118654752f));  // exact gelu
      if (RES) v += resid[(size_t)row * Nc + col];
      C[(size_t)row * Nc + col] = v;
    }
  }
}

// ---------------- fused attention (flash-style, fp32) ----------------
// grid = B*NH*(N/8); block 256 = 4 waves; each wave: 2 rows, lane = key index within 64-tile.
__global__ void attn_k(const float* __restrict__ qkv, const float* __restrict__ distm,
                       const float* __restrict__ tbl_l, float* __restrict__ ctx) {
  int bid = blockIdx.x;
  int it = bid % (N_ / 8);
  int t2 = bid / (N_ / 8);
  int hh = t2 % NH_;
  int b = t2 / NH_;
  int i0 = it * 8;
  __shared__ float Qs[8][32];
  int tid = threadIdx.x;
  {
    int r = tid >> 5, k = tid & 31;
    Qs[r][k] = qkv[(size_t)(b * N_ + i0 + r) * 768 + hh * 32 + k];
  }
  __syncthreads();
  int wave = tid >> 6, lane = tid & 63;
  int ra = wave * 2;
  const float* tblh = tbl_l + (size_t)hh * TBL_STRIDE;
  float pc[2][32];
  float mm[2], ll[2];
#pragma unroll
  for (int r = 0; r < 2; r++) {
    mm[r] = NEGV;
    ll[r] = 0.f;
#pragma unroll
    for (int k = 0; k < 32; k++) pc[r][k] = 0.f;
  }
  for (int jt = 0; jt < 6; jt++) {
    int j = jt * 64 + lane;
    const float* kb = qkv + (size_t)(b * N_ + j) * 768 + 256 + hh * 32;
    const float* vb = kb + 256;
    float Kr[32], Vr[32];
#pragma unroll
    for (int q = 0; q < 8; q++) {
      float4 k4 = *(const float4*)(kb + q * 4);
      Kr[q * 4 + 0] = k4.x; Kr[q * 4 + 1] = k4.y; Kr[q * 4 + 2] = k4.z; Kr[q * 4 + 3] = k4.w;
      float4 v4 = *(const float4*)(vb + q * 4);
      Vr[q * 4 + 0] = v4.x; Vr[q * 4 + 1] = v4.y; Vr[q * 4 + 2] = v4.z; Vr[q * 4 + 3] = v4.w;
    }
#pragma unroll
    for (int r = 0; r < 2; r++) {
      int irow = i0 + ra + r;
      float d = distm[(size_t)(b * N_ + irow) * N_ + j];
      float lg = 0.f;
      const float4* qp = (const float4*)Qs[ra + r];
#pragma unroll
      for (int q = 0; q < 8; q++) {
        float4 qq = qp[q];
        lg += qq.x * Kr[q * 4] + qq.y * Kr[q * 4 + 1] + qq.z * Kr[q * 4 + 2] + qq.w * Kr[q * 4 + 3];
      }
      lg *= INVSC;
      if (d <= CUT) {
        float u = d * ((float)TBL_N / CUT);
        int ix = (int)u;
        ix = ix > TBL_N - 1 ? TBL_N - 1 : ix;
        float fr = u - (float)ix;
        float bias = (j == irow) ? tblh[TBL_N + 1]
                                 : (tblh[ix] * (1.f - fr) + tblh[ix + 1] * fr);
        lg += bias;
      } else {
        lg = NEGV;
      }
      float mt = wave_max(lg);
      float mn = fmaxf(mm[r], mt);
      float al = __expf(mm[r] - mn);
      float p = __expf(lg - mn);
      ll[r] = ll[r] * al + p;
#pragma unroll
      for (int k = 0; k < 32; k++) pc[r][k] = pc[r][k] * al + p * Vr[k];
      mm[r] = mn;
    }
  }
#pragma unroll
  for (int r = 0; r < 2; r++) {
    float Ls = wave_sum(ll[r]);
    float inv = 1.f / Ls;
    float outv = 0.f;
#pragma unroll
    for (int k = 0; k < 32; k++) {
      float v = wave_sum(pc[r][k]);
      outv = (lane == k) ? v : outv;
    }
    if (lane < 32) {
      int irow = i0 + ra + r;
      ctx[(size_t)(b * N_ + irow) * H_ + hh * 32 + lane] = outv * inv;
    }
  }
}

// ---------------- combine: o = ctx * sigmoid(g2) ----------------
__global__ __launch_bounds__(256) void comb_k(const float* __restrict__ ctx,
                                              const float* __restrict__ g2,
                                              float* __restrict__ o) {
  int e = blockIdx.x * 256 + threadIdx.x;
  float g = g2[e];
  o[e] = ctx[e] / (1.f + __expf(-g));
}

// ---------------- energy: masked mean over nodes then dot with eh_w ----------------
__global__ __launch_bounds__(256) void energy_k(const float* __restrict__ p2,
                                                const float* __restrict__ mask,
                                                const float* __restrict__ ehw,
                                                const float* __restrict__ ehb,
                                                float* __restrict__ out) {
  int b = blockIdx.x, h = threadIdx.x;
  float s = 0.f, cnt = 0.f;
  for (int i = 0; i < N_; i++) {
    float m = mask[b * N_ + i] > 0.f ? 1.f : 0.f;
    s += p2[(size_t)(b * N_ + i) * H_ + h] * m;
    cnt += m;
  }
  float val = s * ehw[h];
  __shared__ float red[256];
  red[h] = val;
  __syncthreads();
  for (int st = 128; st > 0; st >>= 1) {
    if (h < st) red[h] += red[h + st];
    __syncthreads();
  }
  if (h == 0) {
    float c = cnt < 1.f ? 1.f : cnt;
    out[b] = red[0] / c + ehb[0];
  }
}

extern "C" void kernel_launch(void* const* d_in, const int* in_sizes, int n_in,
                              void* d_out, int out_size, void* d_ws, size_t ws_size,
                              hipStream_t stream) {
  const int* node_idx = (const int*)d_in[0];
  const float* positions = (const float*)d_in[1];
  const float* mask = (const float*)d_in[2];
  const float* emb = (const float*)d_in[3];
  const float* ln1_g = (const float*)d_in[4];
  const float* ln1_b = (const float*)d_in[5];
  const float* qkv_w = (const float*)d_in[6];
  const float* qkv_b = (const float*)d_in[7];
  const float* out_w = (const float*)d_in[8];
  const float* out_b = (const float*)d_in[9];
  const float* rb_w1 = (const float*)d_in[10];
  const float* rb_b1 = (const float*)d_in[11];
  const float* rb_w2 = (const float*)d_in[12];
  const float* rb_b2 = (const float*)d_in[13];
  const float* gate_w1 = (const float*)d_in[14];
  const float* gate_b1 = (const float*)d_in[15];
  const float* gate_w2 = (const float*)d_in[16];
  const float* gate_b2 = (const float*)d_in[17];
  const float* ln2_g = (const float*)d_in[18];
  const float* ln2_b = (const float*)d_in[19];
  const float* ff_w1 = (const float*)d_in[20];
  const float* ff_b1 = (const float*)d_in[21];
  const float* ff_w2 = (const float*)d_in[22];
  const float* ff_b2 = (const float*)d_in[23];
  const float* pool_g = (const float*)d_in[24];
  const float* pool_beta = (const float*)d_in[25];
  const float* pool_w = (const float*)d_in[26];
  const float* pool_b = (const float*)d_in[27];
  const float* eh_w = (const float*)d_in[28];
  const float* eh_b = (const float*)d_in[29];
  float* eout = (float*)d_out;

  // workspace layout (floats)
  float* Wp = (float*)d_ws;
  float* x = Wp;                         // 393216
  float* h = x + (size_t)M_ * H_;        // 393216
  float* qkvb = h + (size_t)M_ * H_;     // 1179648
  float* ctx = qkvb + (size_t)M_ * 3 * H_;
  float* g1 = ctx + (size_t)M_ * H_;
  float* g2 = g1 + (size_t)M_ * H_;
  float* distm = g2 + (size_t)M_ * H_;        // 589824
  float* tbl = distm + (size_t)B_ * N_ * N_;  // L*NH*4098

  // ---- setup ----
  embed_k<<<M_ * H_ / 256, 256, 0, stream>>>(node_idx, mask, emb, x);
  dist_k<<<B_ * N_ * N_ / 256, 256, 0, stream>>>(positions, mask, distm);
  table_k<<<L_ * TBL_STRIDE, 256, 0, stream>>>(rb_w1, rb_b1, rb_w2, rb_b2, tbl);

  for (int l = 0; l < L_; l++) {
    const float* qw = qkv_w + (size_t)l * H_ * 3 * H_;
    const float* qb = qkv_b + (size_t)l * 3 * H_;
    const float* ow = out_w + (size_t)l * H_ * H_;
    const float* ob = out_b + (size_t)l * H_;
    const float* gw1 = gate_w1 + (size_t)l * H_ * H_;
    const float* gb1 = gate_b1 + (size_t)l * H_;
    const float* gw2 = gate_w2 + (size_t)l * H_ * H_;
    const float* gb2 = gate_b2 + (size_t)l * H_;
    const float* fw1 = ff_w1 + (size_t)l * H_ * 2 * H_;
    const float* fb1 = ff_b1 + (size_t)l * 2 * H_;
    const float* fw2 = ff_w2 + (size_t)l * 2 * H_ * H_;
    const float* fb2 = ff_b2 + (size_t)l * H_;

    // h = LN1(x)
    ln_k<<<M_ / 4, 256, 0, stream>>>(x, ln1_g + l * H_, ln1_b + l * H_, h);
    // qkv = h @ qkv_w + qkv_b
    gemm_k<0, false><<<dim3(3 * H_ / 64, M_ / 64), 256, 0, stream>>>(h, qw, qb, nullptr, qkvb,
                                                                    H_, 3 * H_);
    // ctx = attention(qkv, dist, bias-table)
    attn_k<<<B_ * NH_ * (N_ / 8), 256, 0, stream>>>(qkvb, distm,
                                                    tbl + (size_t)l * NH_ * TBL_STRIDE, ctx);
    // g1 = silu(h @ gate_w1 + gate_b1)
    gemm_k<1, false><<<dim3(H_ / 64, M_ / 64), 256, 0, stream>>>(h, gw1, gb1, nullptr, g1, H_, H_);
    // g2 = g1 @ gate_w2 + gate_b2
    gemm_k<0, false><<<dim3(H_ / 64, M_ / 64), 256, 0, stream>>>(g1, gw2, gb2, nullptr, g2, H_, H_);
    // h <- ctx * sigmoid(g2)   (h is free after gate1)
    comb_k<<<M_ * H_ / 256, 256, 0, stream>>>(ctx, g2, h);
    // x = x + h @ out_w + out_b
    gemm_k<0, true><<<dim3(H_ / 64, M_ / 64), 256, 0, stream>>>(h, ow, ob, x, x, H_, H_);
    // g1 <- LN2(x)
    ln_k<<<M_ / 4, 256, 0, stream>>>(x, ln2_g + l * H_, ln2_b + l * H_, g1);
    // qkvb <- gelu(g1 @ ff_w1 + ff_b1)   [1536 x 512]
    gemm_k<2, false><<<dim3(2 * H_ / 64, M_ / 64), 256, 0, stream>>>(g1, fw1, fb1, nullptr, qkvb,
                                                                    H_, 2 * H_);
    // x = x + qkvb @ ff_w2 + ff_b2
    gemm_k<0, true><<<dim3(H_ / 64, M_ / 64), 256, 0, stream>>>(qkvb, fw2, fb2, x, x, 2 * H_, H_);
  }

  // pooling head
  ln_k<<<M_ / 4, 256, 0, stream>>>(x, pool_g, pool_beta, h);
  gemm_k<1, false><<<dim3(H_ / 64, M_ / 64), 256, 0, stream>>>(h, pool_w, pool_b, nullptr, ctx,
                                                              H_, H_);
  energy_k<<<B_, 256, 0, stream>>>(ctx, mask, eh_w, eh_b, eout);
}

// Round 2
// 1131.761 us; speedup vs baseline: 1.4955x; 1.4955x over previous
//
#include <hip/hip_runtime.h>
#include <hip/hip_bf16.h>
#include <math.h>

// Problem constants (hardcoded from reference)
constexpr int B_ = 4, N_ = 384, H_ = 256, NH_ = 8, DD_ = 32, L_ = 4;
constexpr int M_ = B_ * N_;          // 1536 node rows
constexpr float CUT = 5.0f;
constexpr float PI_ = 3.14159265358979323846f;
constexpr float INVSC = 0.17677669529663687f;  // 1/sqrt(32)
constexpr int TBL_N = 4096;                     // intervals; values at 0..4096, diag at 4097
constexpr int TBL_STRIDE = 4098;
constexpr float NEGV = -3.0e38f;

__device__ __forceinline__ float wave_sum(float v) {
#pragma unroll
  for (int s = 1; s < 64; s <<= 1) v += __shfl_xor(v, s);
  return v;
}
__device__ __forceinline__ float wave_max(float v) {
#pragma unroll
  for (int s = 1; s < 64; s <<= 1) v = fmaxf(v, __shfl_xor(v, s));
  return v;
}

// ---------------- embed: x = emb[idx] * maskb ----------------
__global__ __launch_bounds__(256) void embed_k(const int* __restrict__ idx,
                                               const float* __restrict__ mask,
                                               const float* __restrict__ emb,
                                               float* __restrict__ X) {
  int e = blockIdx.x * 256 + threadIdx.x;   // < M_*H_
  int mrow = e >> 8, c = e & 255;
  float mb = mask[mrow] > 0.f ? 1.f : 0.f;
  X[e] = emb[idx[mrow] * H_ + c] * mb;
}

// ---------------- dist: masked distances ----------------
__global__ __launch_bounds__(256) void dist_k(const float* __restrict__ pos,
                                              const float* __restrict__ mask,
                                              float* __restrict__ distm) {
  int e = blockIdx.x * 256 + threadIdx.x;   // < B*N*N
  int j = e % N_;
  int t = e / N_;
  int i = t % N_;
  int b = t / N_;
  float mi = mask[b * N_ + i], mj = mask[b * N_ + j];
  const float* pi = pos + (size_t)(b * N_ + i) * 3;
  const float* pj = pos + (size_t)(b * N_ + j) * 3;
  float dx = pi[0] - pj[0] + 1e-9f;
  float dy = pi[1] - pj[1] + 1e-9f;
  float dz = pi[2] - pj[2] + 1e-9f;
  float d = sqrtf(dx * dx + dy * dy + dz * dz);
  distm[e] = (mi > 0.f && mj > 0.f) ? d : 1e30f;
}

// ---------------- bias table: g_{l,h}(d) ----------------
// grid = L_*4098 blocks, 256 threads. t in [0,4096] -> d = t*5/4096 ; t==4097 -> diagonal dist
__global__ __launch_bounds__(256) void table_k(const float* __restrict__ rb_w1,
                                               const float* __restrict__ rb_b1,
                                               const float* __restrict__ rb_w2,
                                               const float* __restrict__ rb_b2,
                                               float* __restrict__ tbl) {
  int bid = blockIdx.x;
  int l = bid / TBL_STRIDE;
  int t = bid % TBL_STRIDE;
  int tid = threadIdx.x;
  float d = (t <= TBL_N) ? (t * (CUT / (float)TBL_N)) : 1.7320508075688772e-9f;
  __shared__ float sf[DD_];
  if (tid < DD_) {
    float ang = PI_ * (tid + 1) * d * (1.f / CUT);
    sf[tid] = sinf(ang) / (d + 1e-6f);   // (d<=CUT) always true here
  }
  __syncthreads();
  int h = tid;
  const float* w1 = rb_w1 + (size_t)l * DD_ * H_;
  float pre = rb_b1[l * H_ + h];
#pragma unroll
  for (int k = 0; k < DD_; k++) pre += sf[k] * w1[k * H_ + h];
  float hb = pre / (1.f + expf(-pre));   // silu
  const float* w2 = rb_w2 + (size_t)l * H_ * NH_ + h * NH_;
  float part[NH_];
#pragma unroll
  for (int o = 0; o < NH_; o++) part[o] = hb * w2[o];
#pragma unroll
  for (int o = 0; o < NH_; o++) part[o] = wave_sum(part[o]);
  __shared__ float sacc[4][NH_];
  int wave = tid >> 6, lane = tid & 63;
  if (lane == 0) {
#pragma unroll
    for (int o = 0; o < NH_; o++) sacc[wave][o] = part[o];
  }
  __syncthreads();
  if (tid < NH_) {
    float r = sacc[0][tid] + sacc[1][tid] + sacc[2][tid] + sacc[3][tid] + rb_b2[l * NH_ + tid];
    tbl[(size_t)(l * NH_ + tid) * TBL_STRIDE + t] = r;
  }
}

// ---------------- LayerNorm (row of 256), one wave per row ----------------
__global__ __launch_bounds__(256) void ln_k(const float* __restrict__ X,
                                            const float* __restrict__ g,
                                            const float* __restrict__ bta,
                                            float* __restrict__ O) {
  int wave = threadIdx.x >> 6, lane = threadIdx.x & 63;
  int row = blockIdx.x * 4 + wave;
  const float* xr = X + (size_t)row * H_;
  float4 v = *(const float4*)(xr + lane * 4);
  float s = v.x + v.y + v.z + v.w;
  s = wave_sum(s);
  float m = s * (1.f / H_);
  float dx = v.x - m, dy = v.y - m, dz = v.z - m, dw = v.w - m;
  float vs = dx * dx + dy * dy + dz * dz + dw * dw;
  vs = wave_sum(vs);
  float rs = rsqrtf(vs * (1.f / H_) + 1e-5f);
  float4 gg = *(const float4*)(g + lane * 4);
  float4 bb = *(const float4*)(bta + lane * 4);
  float4 o;
  o.x = dx * rs * gg.x + bb.x;
  o.y = dy * rs * gg.y + bb.y;
  o.z = dz * rs * gg.z + bb.z;
  o.w = dw * rs * gg.w + bb.w;
  *(float4*)(O + (size_t)row * H_ + lane * 4) = o;
}

// ---------------- generic tiled fp32 GEMM: C[M,Nc] = act(A[M,K]@W[K,Nc] + bias) (+resid) ----
// BM=BN=64, BK=16, 256 threads, 4x4 register tile. M fixed = 1536.
template <int ACT, bool RES>
__global__ __launch_bounds__(256) void gemm_k(const float* __restrict__ A,
                                              const float* __restrict__ W,
                                              const float* __restrict__ bias,
                                              const float* __restrict__ resid,
                                              float* __restrict__ C, int K, int Nc) {
  __shared__ float As[16][68];
  __shared__ float Bs[16][64];
  const int n0 = blockIdx.x * 64, m0 = blockIdx.y * 64;
  const int tid = threadIdx.x;
  const int trow = tid >> 4, tcol = tid & 15;
  const int arow = tid >> 2, akq = (tid & 3) << 2;
  const int brow = tid >> 4, bc = (tid & 15) << 2;
  float acc[4][4] = {};
  for (int k0 = 0; k0 < K; k0 += 16) {
    float4 av = *(const float4*)(A + (size_t)(m0 + arow) * K + k0 + akq);
    As[akq + 0][arow] = av.x;
    As[akq + 1][arow] = av.y;
    As[akq + 2][arow] = av.z;
    As[akq + 3][arow] = av.w;
    *(float4*)(&Bs[brow][bc]) = *(const float4*)(W + (size_t)(k0 + brow) * Nc + n0 + bc);
    __syncthreads();
#pragma unroll
    for (int kk = 0; kk < 16; kk++) {
      float4 a = *(const float4*)(&As[kk][trow << 2]);
      float4 b = *(const float4*)(&Bs[kk][tcol << 2]);
      float aa[4] = {a.x, a.y, a.z, a.w};
      float bb[4] = {b.x, b.y, b.z, b.w};
#pragma unroll
      for (int i = 0; i < 4; i++)
#pragma unroll
        for (int j = 0; j < 4; j++) acc[i][j] += aa[i] * bb[j];
    }
    __syncthreads();
  }
#pragma unroll
  for (int i = 0; i < 4; i++) {
    int row = m0 + (trow << 2) + i;
#pragma unroll
    for (int j = 0; j < 4; j++) {
      int col = n0 + (tcol << 2) + j;
      float v = acc[i][j] + bias[col];
      if (ACT == 1) v = v / (1.f + __expf(-v));                       // silu
      if (ACT == 2) v = 0.5f * v * (1.f + erff(v * 0.70710678118654752f));  // exact gelu
      if (RES) v += resid[(size_t)row * Nc + col];
      C[(size_t)row * Nc + col] = v;
    }
  }
}

// ---------------- fused attention (flash-style, fp32) ----------------
// grid = B*NH*(N/8); block 256 = 4 waves; each wave: 2 rows, lane = key index within 64-tile.
// __launch_bounds__(256) is ESSENTIAL: without it hipcc compiles for 1024-thread
// blocks and caps VGPRs at 64 -> pc/Kr/Vr spill to scratch (348 MB of scratch
// writes per dispatch measured in round 1).
__global__ __launch_bounds__(256) void attn_k(const float* __restrict__ qkv,
                                              const float* __restrict__ distm,
                                              const float* __restrict__ tbl_l,
                                              float* __restrict__ ctx) {
  int bid = blockIdx.x;
  int it = bid % (N_ / 8);
  int t2 = bid / (N_ / 8);
  int hh = t2 % NH_;
  int b = t2 / NH_;
  int i0 = it * 8;
  __shared__ float Qs[8][32];
  int tid = threadIdx.x;
  {
    int r = tid >> 5, k = tid & 31;
    Qs[r][k] = qkv[(size_t)(b * N_ + i0 + r) * 768 + hh * 32 + k];
  }
  __syncthreads();
  int wave = tid >> 6, lane = tid & 63;
  int ra = wave * 2;
  const float* tblh = tbl_l + (size_t)hh * TBL_STRIDE;
  float pc[2][32];
  float mm[2], ll[2];
#pragma unroll
  for (int r = 0; r < 2; r++) {
    mm[r] = NEGV;
    ll[r] = 0.f;
#pragma unroll
    for (int k = 0; k < 32; k++) pc[r][k] = 0.f;
  }
  for (int jt = 0; jt < 6; jt++) {
    int j = jt * 64 + lane;
    const float* kb = qkv + (size_t)(b * N_ + j) * 768 + 256 + hh * 32;
    const float* vb = kb + 256;
    float Kr[32], Vr[32];
#pragma unroll
    for (int q = 0; q < 8; q++) {
      float4 k4 = *(const float4*)(kb + q * 4);
      Kr[q * 4 + 0] = k4.x; Kr[q * 4 + 1] = k4.y; Kr[q * 4 + 2] = k4.z; Kr[q * 4 + 3] = k4.w;
      float4 v4 = *(const float4*)(vb + q * 4);
      Vr[q * 4 + 0] = v4.x; Vr[q * 4 + 1] = v4.y; Vr[q * 4 + 2] = v4.z; Vr[q * 4 + 3] = v4.w;
    }
#pragma unroll
    for (int r = 0; r < 2; r++) {
      int irow = i0 + ra + r;
      float d = distm[(size_t)(b * N_ + irow) * N_ + j];
      float lg = 0.f;
      const float4* qp = (const float4*)Qs[ra + r];
#pragma unroll
      for (int q = 0; q < 8; q++) {
        float4 qq = qp[q];
        lg += qq.x * Kr[q * 4] + qq.y * Kr[q * 4 + 1] + qq.z * Kr[q * 4 + 2] + qq.w * Kr[q * 4 + 3];
      }
      lg *= INVSC;
      if (d <= CUT) {
        float u = d * ((float)TBL_N / CUT);
        int ix = (int)u;
        ix = ix > TBL_N - 1 ? TBL_N - 1 : ix;
        float fr = u - (float)ix;
        float bias = (j == irow) ? tblh[TBL_N + 1]
                                 : (tblh[ix] * (1.f - fr) + tblh[ix + 1] * fr);
        lg += bias;
      } else {
        lg = NEGV;
      }
      float mt = wave_max(lg);
      float mn = fmaxf(mm[r], mt);
      float al = __expf(mm[r] - mn);
      float p = __expf(lg - mn);
      ll[r] = ll[r] * al + p;
#pragma unroll
      for (int k = 0; k < 32; k++) pc[r][k] = pc[r][k] * al + p * Vr[k];
      mm[r] = mn;
    }
  }
#pragma unroll
  for (int r = 0; r < 2; r++) {
    float Ls = wave_sum(ll[r]);
    float inv = 1.f / Ls;
    float outv = 0.f;
#pragma unroll
    for (int k = 0; k < 32; k++) {
      float v = wave_sum(pc[r][k]);
      outv = (lane == k) ? v : outv;
    }
    if (lane < 32) {
      int irow = i0 + ra + r;
      ctx[(size_t)(b * N_ + irow) * H_ + hh * 32 + lane] = outv * inv;
    }
  }
}

// ---------------- combine: o = ctx * sigmoid(g2) ----------------
__global__ __launch_bounds__(256) void comb_k(const float* __restrict__ ctx,
                                              const float* __restrict__ g2,
                                              float* __restrict__ o) {
  int e = blockIdx.x * 256 + threadIdx.x;
  float g = g2[e];
  o[e] = ctx[e] / (1.f + __expf(-g));
}

// ---------------- energy: masked mean over nodes then dot with eh_w ----------------
__global__ __launch_bounds__(256) void energy_k(const float* __restrict__ p2,
                                                const float* __restrict__ mask,
                                                const float* __restrict__ ehw,
                                                const float* __restrict__ ehb,
                                                float* __restrict__ out) {
  int b = blockIdx.x, h = threadIdx.x;
  float s = 0.f, cnt = 0.f;
  for (int i = 0; i < N_; i++) {
    float m = mask[b * N_ + i] > 0.f ? 1.f : 0.f;
    s += p2[(size_t)(b * N_ + i) * H_ + h] * m;
    cnt += m;
  }
  float val = s * ehw[h];
  __shared__ float red[256];
  red[h] = val;
  __syncthreads();
  for (int st = 128; st > 0; st >>= 1) {
    if (h < st) red[h] += red[h + st];
    __syncthreads();
  }
  if (h == 0) {
    float c = cnt < 1.f ? 1.f : cnt;
    out[b] = red[0] / c + ehb[0];
  }
}

extern "C" void kernel_launch(void* const* d_in, const int* in_sizes, int n_in,
                              void* d_out, int out_size, void* d_ws, size_t ws_size,
                              hipStream_t stream) {
  const int* node_idx = (const int*)d_in[0];
  const float* positions = (const float*)d_in[1];
  const float* mask = (const float*)d_in[2];
  const float* emb = (const float*)d_in[3];
  const float* ln1_g = (const float*)d_in[4];
  const float* ln1_b = (const float*)d_in[5];
  const float* qkv_w = (const float*)d_in[6];
  const float* qkv_b = (const float*)d_in[7];
  const float* out_w = (const float*)d_in[8];
  const float* out_b = (const float*)d_in[9];
  const float* rb_w1 = (const float*)d_in[10];
  const float* rb_b1 = (const float*)d_in[11];
  const float* rb_w2 = (const float*)d_in[12];
  const float* rb_b2 = (const float*)d_in[13];
  const float* gate_w1 = (const float*)d_in[14];
  const float* gate_b1 = (const float*)d_in[15];
  const float* gate_w2 = (const float*)d_in[16];
  const float* gate_b2 = (const float*)d_in[17];
  const float* ln2_g = (const float*)d_in[18];
  const float* ln2_b = (const float*)d_in[19];
  const float* ff_w1 = (const float*)d_in[20];
  const float* ff_b1 = (const float*)d_in[21];
  const float* ff_w2 = (const float*)d_in[22];
  const float* ff_b2 = (const float*)d_in[23];
  const float* pool_g = (const float*)d_in[24];
  const float* pool_beta = (const float*)d_in[25];
  const float* pool_w = (const float*)d_in[26];
  const float* pool_b = (const float*)d_in[27];
  const float* eh_w = (const float*)d_in[28];
  const float* eh_b = (const float*)d_in[29];
  float* eout = (float*)d_out;

  // workspace layout (floats)
  float* Wp = (float*)d_ws;
  float* x = Wp;                         // 393216
  float* h = x + (size_t)M_ * H_;        // 393216
  float* qkvb = h + (size_t)M_ * H_;     // 1179648
  float* ctx = qkvb + (size_t)M_ * 3 * H_;
  float* g1 = ctx + (size_t)M_ * H_;
  float* g2 = g1 + (size_t)M_ * H_;
  float* distm = g2 + (size_t)M_ * H_;        // 589824
  float* tbl = distm + (size_t)B_ * N_ * N_;  // L*NH*4098

  // ---- setup ----
  embed_k<<<M_ * H_ / 256, 256, 0, stream>>>(node_idx, mask, emb, x);
  dist_k<<<B_ * N_ * N_ / 256, 256, 0, stream>>>(positions, mask, distm);
  table_k<<<L_ * TBL_STRIDE, 256, 0, stream>>>(rb_w1, rb_b1, rb_w2, rb_b2, tbl);

  for (int l = 0; l < L_; l++) {
    const float* qw = qkv_w + (size_t)l * H_ * 3 * H_;
    const float* qb = qkv_b + (size_t)l * 3 * H_;
    const float* ow = out_w + (size_t)l * H_ * H_;
    const float* ob = out_b + (size_t)l * H_;
    const float* gw1 = gate_w1 + (size_t)l * H_ * H_;
    const float* gb1 = gate_b1 + (size_t)l * H_;
    const float* gw2 = gate_w2 + (size_t)l * H_ * H_;
    const float* gb2 = gate_b2 + (size_t)l * H_;
    const float* fw1 = ff_w1 + (size_t)l * H_ * 2 * H_;
    const float* fb1 = ff_b1 + (size_t)l * 2 * H_;
    const float* fw2 = ff_w2 + (size_t)l * 2 * H_ * H_;
    const float* fb2 = ff_b2 + (size_t)l * H_;

    // h = LN1(x)
    ln_k<<<M_ / 4, 256, 0, stream>>>(x, ln1_g + l * H_, ln1_b + l * H_, h);
    // qkv = h @ qkv_w + qkv_b
    gemm_k<0, false><<<dim3(3 * H_ / 64, M_ / 64), 256, 0, stream>>>(h, qw, qb, nullptr, qkvb,
                                                                    H_, 3 * H_);
    // ctx = attention(qkv, dist, bias-table)
    attn_k<<<B_ * NH_ * (N_ / 8), 256, 0, stream>>>(qkvb, distm,
                                                    tbl + (size_t)l * NH_ * TBL_STRIDE, ctx);
    // g1 = silu(h @ gate_w1 + gate_b1)
    gemm_k<1, false><<<dim3(H_ / 64, M_ / 64), 256, 0, stream>>>(h, gw1, gb1, nullptr, g1, H_, H_);
    // g2 = g1 @ gate_w2 + gate_b2
    gemm_k<0, false><<<dim3(H_ / 64, M_ / 64), 256, 0, stream>>>(g1, gw2, gb2, nullptr, g2, H_, H_);
    // h <- ctx * sigmoid(g2)   (h is free after gate1)
    comb_k<<<M_ * H_ / 256, 256, 0, stream>>>(ctx, g2, h);
    // x = x + h @ out_w + out_b
    gemm_k<0, true><<<dim3(H_ / 64, M_ / 64), 256, 0, stream>>>(h, ow, ob, x, x, H_, H_);
    // g1 <- LN2(x)
    ln_k<<<M_ / 4, 256, 0, stream>>>(x, ln2_g + l * H_, ln2_b + l * H_, g1);
    // qkvb <- gelu(g1 @ ff_w1 + ff_b1)   [1536 x 512]
    gemm_k<2, false><<<dim3(2 * H_ / 64, M_ / 64), 256, 0, stream>>>(g1, fw1, fb1, nullptr, qkvb,
                                                                    H_, 2 * H_);
    // x = x + qkvb @ ff_w2 + ff_b2
    gemm_k<0, true><<<dim3(H_ / 64, M_ / 64), 256, 0, stream>>>(qkvb, fw2, fb2, x, x, 2 * H_, H_);
  }

  // pooling head
  ln_k<<<M_ / 4, 256, 0, stream>>>(x, pool_g, pool_beta, h);
  gemm_k<1, false><<<dim3(H_ / 64, M_ / 64), 256, 0, stream>>>(h, pool_w, pool_b, nullptr, ctx,
                                                              H_, H_);
  energy_k<<<B_, 256, 0, stream>>>(ctx, mask, eh_w, eh_b, eout);
}

// Round 4
// 944.483 us; speedup vs baseline: 1.7920x; 1.1983x over previous
//
#include <hip/hip_runtime.h>
#include <hip/hip_bf16.h>
#include <math.h>

// Problem constants (hardcoded from reference)
constexpr int B_ = 4, N_ = 384, H_ = 256, NH_ = 8, DD_ = 32, L_ = 4;
constexpr int M_ = B_ * N_;          // 1536 node rows
constexpr float CUT = 5.0f;
constexpr float PI_ = 3.14159265358979323846f;
constexpr float INVSC = 0.17677669529663687f;  // 1/sqrt(32)
constexpr int TBL_N = 4096;                     // intervals; values at 0..4096, diag at 4097
constexpr int TBL_STRIDE = 4098;
constexpr float NEGV = -3.0e38f;

__device__ __forceinline__ float wave_sum(float v) {
#pragma unroll
  for (int s = 1; s < 64; s <<= 1) v += __shfl_xor(v, s);
  return v;
}
__device__ __forceinline__ float wave_max(float v) {
#pragma unroll
  for (int s = 1; s < 64; s <<= 1) v = fmaxf(v, __shfl_xor(v, s));
  return v;
}

// ---------------- embed: x = emb[idx] * maskb ----------------
__global__ __launch_bounds__(256) void embed_k(const int* __restrict__ idx,
                                               const float* __restrict__ mask,
                                               const float* __restrict__ emb,
                                               float* __restrict__ X) {
  int e = blockIdx.x * 256 + threadIdx.x;   // < M_*H_
  int mrow = e >> 8, c = e & 255;
  float mb = mask[mrow] > 0.f ? 1.f : 0.f;
  X[e] = emb[idx[mrow] * H_ + c] * mb;
}

// ---------------- dist: masked distances ----------------
__global__ __launch_bounds__(256) void dist_k(const float* __restrict__ pos,
                                              const float* __restrict__ mask,
                                              float* __restrict__ distm) {
  int e = blockIdx.x * 256 + threadIdx.x;   // < B*N*N
  int j = e % N_;
  int t = e / N_;
  int i = t % N_;
  int b = t / N_;
  float mi = mask[b * N_ + i], mj = mask[b * N_ + j];
  const float* pi = pos + (size_t)(b * N_ + i) * 3;
  const float* pj = pos + (size_t)(b * N_ + j) * 3;
  float dx = pi[0] - pj[0] + 1e-9f;
  float dy = pi[1] - pj[1] + 1e-9f;
  float dz = pi[2] - pj[2] + 1e-9f;
  float d = sqrtf(dx * dx + dy * dy + dz * dz);
  distm[e] = (mi > 0.f && mj > 0.f) ? d : 1e30f;
}

// ---------------- bias table: g_{l,h}(d) ----------------
__global__ __launch_bounds__(256) void table_k(const float* __restrict__ rb_w1,
                                               const float* __restrict__ rb_b1,
                                               const float* __restrict__ rb_w2,
                                               const float* __restrict__ rb_b2,
                                               float* __restrict__ tbl) {
  int bid = blockIdx.x;
  int l = bid / TBL_STRIDE;
  int t = bid % TBL_STRIDE;
  int tid = threadIdx.x;
  float d = (t <= TBL_N) ? (t * (CUT / (float)TBL_N)) : 1.7320508075688772e-9f;
  __shared__ float sf[DD_];
  if (tid < DD_) {
    float ang = PI_ * (tid + 1) * d * (1.f / CUT);
    sf[tid] = sinf(ang) / (d + 1e-6f);
  }
  __syncthreads();
  int h = tid;
  const float* w1 = rb_w1 + (size_t)l * DD_ * H_;
  float pre = rb_b1[l * H_ + h];
#pragma unroll
  for (int k = 0; k < DD_; k++) pre += sf[k] * w1[k * H_ + h];
  float hb = pre / (1.f + expf(-pre));   // silu
  const float* w2 = rb_w2 + (size_t)l * H_ * NH_ + h * NH_;
  float part[NH_];
#pragma unroll
  for (int o = 0; o < NH_; o++) part[o] = hb * w2[o];
#pragma unroll
  for (int o = 0; o < NH_; o++) part[o] = wave_sum(part[o]);
  __shared__ float sacc[4][NH_];
  int wave = tid >> 6, lane = tid & 63;
  if (lane == 0) {
#pragma unroll
    for (int o = 0; o < NH_; o++) sacc[wave][o] = part[o];
  }
  __syncthreads();
  if (tid < NH_) {
    float r = sacc[0][tid] + sacc[1][tid] + sacc[2][tid] + sacc[3][tid] + rb_b2[l * NH_ + tid];
    tbl[(size_t)(l * NH_ + tid) * TBL_STRIDE + t] = r;
  }
}

// ---------------- LayerNorm (row of 256), one wave per row ----------------
__global__ __launch_bounds__(256) void ln_k(const float* __restrict__ X,
                                            const float* __restrict__ g,
                                            const float* __restrict__ bta,
                                            float* __restrict__ O) {
  int wave = threadIdx.x >> 6, lane = threadIdx.x & 63;
  int row = blockIdx.x * 4 + wave;
  const float* xr = X + (size_t)row * H_;
  float4 v = *(const float4*)(xr + lane * 4);
  float s = v.x + v.y + v.z + v.w;
  s = wave_sum(s);
  float m = s * (1.f / H_);
  float dx = v.x - m, dy = v.y - m, dz = v.z - m, dw = v.w - m;
  float vs = dx * dx + dy * dy + dz * dz + dw * dw;
  vs = wave_sum(vs);
  float rs = rsqrtf(vs * (1.f / H_) + 1e-5f);
  float4 gg = *(const float4*)(g + lane * 4);
  float4 bb = *(const float4*)(bta + lane * 4);
  float4 o;
  o.x = dx * rs * gg.x + bb.x;
  o.y = dy * rs * gg.y + bb.y;
  o.z = dz * rs * gg.z + bb.z;
  o.w = dw * rs * gg.w + bb.w;
  *(float4*)(O + (size_t)row * H_ + lane * 4) = o;
}

// ---------------- generic tiled fp32 GEMM ----------------
// C[M,Nc] = act(A'[M,K] @ W[K,Nc] + bias) (+resid), A' = PRE ? A*sigmoid(G) : A
// BM=BN=64, BK=16, 256 threads, 4x4 register tile.
template <int ACT, bool RES, bool PRE>
__global__ __launch_bounds__(256) void gemm_k(const float* __restrict__ A,
                                              const float* __restrict__ W,
                                              const float* __restrict__ bias,
                                              const float* __restrict__ resid,
                                              float* __restrict__ C, int K, int Nc,
                                              const float* __restrict__ G) {
  __shared__ float As[16][68];
  __shared__ float Bs[16][64];
  const int n0 = blockIdx.x * 64, m0 = blockIdx.y * 64;
  const int tid = threadIdx.x;
  const int trow = tid >> 4, tcol = tid & 15;
  const int arow = tid >> 2, akq = (tid & 3) << 2;
  const int brow = tid >> 4, bc = (tid & 15) << 2;
  float acc[4][4] = {};
  for (int k0 = 0; k0 < K; k0 += 16) {
    float4 av = *(const float4*)(A + (size_t)(m0 + arow) * K + k0 + akq);
    if (PRE) {
      float4 gv = *(const float4*)(G + (size_t)(m0 + arow) * K + k0 + akq);
      av.x *= 1.f / (1.f + __expf(-gv.x));
      av.y *= 1.f / (1.f + __expf(-gv.y));
      av.z *= 1.f / (1.f + __expf(-gv.z));
      av.w *= 1.f / (1.f + __expf(-gv.w));
    }
    As[akq + 0][arow] = av.x;
    As[akq + 1][arow] = av.y;
    As[akq + 2][arow] = av.z;
    As[akq + 3][arow] = av.w;
    *(float4*)(&Bs[brow][bc]) = *(const float4*)(W + (size_t)(k0 + brow) * Nc + n0 + bc);
    __syncthreads();
#pragma unroll
    for (int kk = 0; kk < 16; kk++) {
      float4 a = *(const float4*)(&As[kk][trow << 2]);
      float4 b = *(const float4*)(&Bs[kk][tcol << 2]);
      float aa[4] = {a.x, a.y, a.z, a.w};
      float bb[4] = {b.x, b.y, b.z, b.w};
#pragma unroll
      for (int i = 0; i < 4; i++)
#pragma unroll
        for (int j = 0; j < 4; j++) acc[i][j] += aa[i] * bb[j];
    }
    __syncthreads();
  }
#pragma unroll
  for (int i = 0; i < 4; i++) {
    int row = m0 + (trow << 2) + i;
#pragma unroll
    for (int j = 0; j < 4; j++) {
      int col = n0 + (tcol << 2) + j;
      float v = acc[i][j] + bias[col];
      if (ACT == 1) v = v / (1.f + __expf(-v));                       // silu
      if (ACT == 2) v = 0.5f * v * (1.f + erff(v * 0.70710678118654752f));  // exact gelu
      if (RES) v += resid[(size_t)row * Nc + col];
      C[(size_t)row * Nc + col] = v;
    }
  }
}

// ---------------- fused attention (flash-style, fp32, LDS-staged K/V) ----------------
// grid = B*NH*(N/8); block 256 = 4 waves; each wave: 2 rows, lane = key index in 64-tile.
// K/V tiles are cooperatively staged into LDS (coalesced) with an XOR swizzle
// (float4-slot ^= row&7, row stride 32 floats) so per-lane row reads hit the
// ds_read_b128 8-cycle floor instead of the stride-128B 32-way bank conflict.
// Next tile's global loads are issued before compute (reg prefetch, T14).
__global__ __launch_bounds__(256) void attn_k(const float* __restrict__ qkv,
                                              const float* __restrict__ distm,
                                              const float* __restrict__ tbl_l,
                                              float* __restrict__ ctx) {
  int bid = blockIdx.x;
  int it = bid % (N_ / 8);
  int t2 = bid / (N_ / 8);
  int hh = t2 % NH_;
  int b = t2 / NH_;
  int i0 = it * 8;
  __shared__ float Qs[8][32];
  __shared__ float Ks[64][32];
  __shared__ float Vs[64][32];
  int tid = threadIdx.x;
  {
    int r = tid >> 5, k = tid & 31;
    Qs[r][k] = qkv[(size_t)(b * N_ + i0 + r) * 768 + hh * 32 + k];
  }
  int wave = tid >> 6, lane = tid & 63;
  int ra = wave * 2;
  const float* tblh = tbl_l + (size_t)hh * TBL_STRIDE;
  float pc[2][32];
  float mm[2], ll[2];
#pragma unroll
  for (int r = 0; r < 2; r++) {
    mm[r] = NEGV;
    ll[r] = 0.f;
#pragma unroll
    for (int k = 0; k < 32; k++) pc[r][k] = 0.f;
  }
  // staging map: thread -> rows (r0, r0+32), float4 col slot sc
  const int r0 = tid >> 3;          // 0..31
  const int sc = tid & 7;           // float4 slot 0..7
  const int pcol = (sc ^ (r0 & 7)) << 2;  // swizzled physical col (floats)
  const size_t bb = (size_t)b * N_;
  float4 sk0, sk1, sv0, sv1;
  {
    const float* p0 = qkv + (bb + r0) * 768 + 256 + hh * 32 + (sc << 2);
    sk0 = *(const float4*)p0;
    sk1 = *(const float4*)(p0 + 32 * 768);
    sv0 = *(const float4*)(p0 + 256);
    sv1 = *(const float4*)(p0 + 32 * 768 + 256);
  }
  for (int jt = 0; jt < 6; jt++) {
    __syncthreads();                 // previous tile's compute done; LDS free
    *(float4*)&Ks[r0][pcol] = sk0;
    *(float4*)&Ks[r0 + 32][pcol] = sk1;
    *(float4*)&Vs[r0][pcol] = sv0;
    *(float4*)&Vs[r0 + 32][pcol] = sv1;
    __syncthreads();                 // LDS tile ready
    if (jt < 5) {                    // prefetch next tile (overlaps compute)
      const float* p0 = qkv + (bb + (jt + 1) * 64 + r0) * 768 + 256 + hh * 32 + (sc << 2);
      sk0 = *(const float4*)p0;
      sk1 = *(const float4*)(p0 + 32 * 768);
      sv0 = *(const float4*)(p0 + 256);
      sv1 = *(const float4*)(p0 + 32 * 768 + 256);
    }
    // read this lane's K/V row from LDS (swizzled)
    float Kr[32], Vr[32];
    const int lsw = lane & 7;
#pragma unroll
    for (int q = 0; q < 8; q++) {
      *(float4*)&Kr[q * 4] = *(const float4*)&Ks[lane][(q ^ lsw) << 2];
      *(float4*)&Vr[q * 4] = *(const float4*)&Vs[lane][(q ^ lsw) << 2];
    }
    int j = jt * 64 + lane;
#pragma unroll
    for (int r = 0; r < 2; r++) {
      int irow = i0 + ra + r;
      float d = distm[(bb + irow) * N_ + j];
      float lg = 0.f;
      const float4* qp = (const float4*)Qs[ra + r];
#pragma unroll
      for (int q = 0; q < 8; q++) {
        float4 qq = qp[q];
        lg += qq.x * Kr[q * 4] + qq.y * Kr[q * 4 + 1] + qq.z * Kr[q * 4 + 2] + qq.w * Kr[q * 4 + 3];
      }
      lg *= INVSC;
      if (d <= CUT) {
        float u = d * ((float)TBL_N / CUT);
        int ix = (int)u;
        ix = ix > TBL_N - 1 ? TBL_N - 1 : ix;
        float fr = u - (float)ix;
        float bias = (j == irow) ? tblh[TBL_N + 1]
                                 : (tblh[ix] * (1.f - fr) + tblh[ix + 1] * fr);
        lg += bias;
      } else {
        lg = NEGV;
      }
      float mt = wave_max(lg);
      float mn = fmaxf(mm[r], mt);
      float al = __expf(mm[r] - mn);
      float p = __expf(lg - mn);
      ll[r] = ll[r] * al + p;
#pragma unroll
      for (int k = 0; k < 32; k++) pc[r][k] = pc[r][k] * al + p * Vr[k];
      mm[r] = mn;
    }
  }
#pragma unroll
  for (int r = 0; r < 2; r++) {
    float Ls = wave_sum(ll[r]);
    float inv = 1.f / Ls;
    float outv = 0.f;
#pragma unroll
    for (int k = 0; k < 32; k++) {
      float v = wave_sum(pc[r][k]);
      outv = (lane == k) ? v : outv;
    }
    if (lane < 32) {
      int irow = i0 + ra + r;
      ctx[(bb + irow) * H_ + hh * 32 + lane] = outv * inv;
    }
  }
}

// ---------------- energy: masked mean over nodes then dot with eh_w ----------------
__global__ __launch_bounds__(256) void energy_k(const float* __restrict__ p2,
                                                const float* __restrict__ mask,
                                                const float* __restrict__ ehw,
                                                const float* __restrict__ ehb,
                                                float* __restrict__ out) {
  int b = blockIdx.x, h = threadIdx.x;
  float s = 0.f, cnt = 0.f;
  for (int i = 0; i < N_; i++) {
    float m = mask[b * N_ + i] > 0.f ? 1.f : 0.f;
    s += p2[(size_t)(b * N_ + i) * H_ + h] * m;
    cnt += m;
  }
  float val = s * ehw[h];
  __shared__ float red[256];
  red[h] = val;
  __syncthreads();
  for (int st = 128; st > 0; st >>= 1) {
    if (h < st) red[h] += red[h + st];
    __syncthreads();
  }
  if (h == 0) {
    float c = cnt < 1.f ? 1.f : cnt;
    out[b] = red[0] / c + ehb[0];
  }
}

extern "C" void kernel_launch(void* const* d_in, const int* in_sizes, int n_in,
                              void* d_out, int out_size, void* d_ws, size_t ws_size,
                              hipStream_t stream) {
  const int* node_idx = (const int*)d_in[0];
  const float* positions = (const float*)d_in[1];
  const float* mask = (const float*)d_in[2];
  const float* emb = (const float*)d_in[3];
  const float* ln1_g = (const float*)d_in[4];
  const float* ln1_b = (const float*)d_in[5];
  const float* qkv_w = (const float*)d_in[6];
  const float* qkv_b = (const float*)d_in[7];
  const float* out_w = (const float*)d_in[8];
  const float* out_b = (const float*)d_in[9];
  const float* rb_w1 = (const float*)d_in[10];
  const float* rb_b1 = (const float*)d_in[11];
  const float* rb_w2 = (const float*)d_in[12];
  const float* rb_b2 = (const float*)d_in[13];
  const float* gate_w1 = (const float*)d_in[14];
  const float* gate_b1 = (const float*)d_in[15];
  const float* gate_w2 = (const float*)d_in[16];
  const float* gate_b2 = (const float*)d_in[17];
  const float* ln2_g = (const float*)d_in[18];
  const float* ln2_b = (const float*)d_in[19];
  const float* ff_w1 = (const float*)d_in[20];
  const float* ff_b1 = (const float*)d_in[21];
  const float* ff_w2 = (const float*)d_in[22];
  const float* ff_b2 = (const float*)d_in[23];
  const float* pool_g = (const float*)d_in[24];
  const float* pool_beta = (const float*)d_in[25];
  const float* pool_w = (const float*)d_in[26];
  const float* pool_b = (const float*)d_in[27];
  const float* eh_w = (const float*)d_in[28];
  const float* eh_b = (const float*)d_in[29];
  float* eout = (float*)d_out;

  // workspace layout (floats)
  float* Wp = (float*)d_ws;
  float* x = Wp;                         // M*H
  float* h = x + (size_t)M_ * H_;        // M*H
  float* qkvb = h + (size_t)M_ * H_;     // M*3H
  float* ctx = qkvb + (size_t)M_ * 3 * H_;
  float* g1 = ctx + (size_t)M_ * H_;
  float* g2 = g1 + (size_t)M_ * H_;
  float* distm = g2 + (size_t)M_ * H_;        // B*N*N
  float* tbl = distm + (size_t)B_ * N_ * N_;  // L*NH*4098

  // ---- setup ----
  embed_k<<<M_ * H_ / 256, 256, 0, stream>>>(node_idx, mask, emb, x);
  dist_k<<<B_ * N_ * N_ / 256, 256, 0, stream>>>(positions, mask, distm);
  table_k<<<L_ * TBL_STRIDE, 256, 0, stream>>>(rb_w1, rb_b1, rb_w2, rb_b2, tbl);

  for (int l = 0; l < L_; l++) {
    const float* qw = qkv_w + (size_t)l * H_ * 3 * H_;
    const float* qb = qkv_b + (size_t)l * 3 * H_;
    const float* ow = out_w + (size_t)l * H_ * H_;
    const float* ob = out_b + (size_t)l * H_;
    const float* gw1 = gate_w1 + (size_t)l * H_ * H_;
    const float* gb1 = gate_b1 + (size_t)l * H_;
    const float* gw2 = gate_w2 + (size_t)l * H_ * H_;
    const float* gb2 = gate_b2 + (size_t)l * H_;
    const float* fw1 = ff_w1 + (size_t)l * H_ * 2 * H_;
    const float* fb1 = ff_b1 + (size_t)l * 2 * H_;
    const float* fw2 = ff_w2 + (size_t)l * 2 * H_ * H_;
    const float* fb2 = ff_b2 + (size_t)l * H_;

    // h = LN1(x)
    ln_k<<<M_ / 4, 256, 0, stream>>>(x, ln1_g + l * H_, ln1_b + l * H_, h);
    // qkv = h @ qkv_w + qkv_b
    gemm_k<0, false, false><<<dim3(3 * H_ / 64, M_ / 64), 256, 0, stream>>>(
        h, qw, qb, nullptr, qkvb, H_, 3 * H_, nullptr);
    // ctx = attention(qkv, dist, bias-table)
    attn_k<<<B_ * NH_ * (N_ / 8), 256, 0, stream>>>(qkvb, distm,
                                                    tbl + (size_t)l * NH_ * TBL_STRIDE, ctx);
    // g1 = silu(h @ gate_w1 + gate_b1)
    gemm_k<1, false, false><<<dim3(H_ / 64, M_ / 64), 256, 0, stream>>>(
        h, gw1, gb1, nullptr, g1, H_, H_, nullptr);
    // g2 = g1 @ gate_w2 + gate_b2
    gemm_k<0, false, false><<<dim3(H_ / 64, M_ / 64), 256, 0, stream>>>(
        g1, gw2, gb2, nullptr, g2, H_, H_, nullptr);
    // x = x + (ctx * sigmoid(g2)) @ out_w + out_b   (comb fused into A-staging)
    gemm_k<0, true, true><<<dim3(H_ / 64, M_ / 64), 256, 0, stream>>>(
        ctx, ow, ob, x, x, H_, H_, g2);
    // g1 <- LN2(x)
    ln_k<<<M_ / 4, 256, 0, stream>>>(x, ln2_g + l * H_, ln2_b + l * H_, g1);
    // qkvb <- gelu(g1 @ ff_w1 + ff_b1)   [1536 x 512]
    gemm_k<2, false, false><<<dim3(2 * H_ / 64, M_ / 64), 256, 0, stream>>>(
        g1, fw1, fb1, nullptr, qkvb, H_, 2 * H_, nullptr);
    // x = x + qkvb @ ff_w2 + ff_b2
    gemm_k<0, true, false><<<dim3(H_ / 64, M_ / 64), 256, 0, stream>>>(
        qkvb, fw2, fb2, x, x, 2 * H_, H_, nullptr);
  }

  // pooling head
  ln_k<<<M_ / 4, 256, 0, stream>>>(x, pool_g, pool_beta, h);
  gemm_k<1, false, false><<<dim3(H_ / 64, M_ / 64), 256, 0, stream>>>(
      h, pool_w, pool_b, nullptr, ctx, H_, H_, nullptr);
  energy_k<<<B_, 256, 0, stream>>>(ctx, mask, eh_w, eh_b, eout);
}

// Round 5
// 637.579 us; speedup vs baseline: 2.6546x; 1.4814x over previous
//
#include <hip/hip_runtime.h>
#include <hip/hip_bf16.h>
#include <math.h>

// Problem constants (hardcoded from reference)
constexpr int B_ = 4, N_ = 384, H_ = 256, NH_ = 8, DD_ = 32, L_ = 4;
constexpr int M_ = B_ * N_;          // 1536 node rows
constexpr float CUT = 5.0f;
constexpr float PI_ = 3.14159265358979323846f;
constexpr float INVSC = 0.17677669529663687f;  // 1/sqrt(32)
constexpr int TBL_N = 4096;
constexpr int TBL_STRIDE = 4098;
constexpr float NEGV = -3.0e38f;

typedef __attribute__((ext_vector_type(8))) short short8;
typedef __attribute__((ext_vector_type(4))) float f32x4;
typedef __attribute__((ext_vector_type(4))) unsigned short u16x4;
using u16 = unsigned short;

__device__ __forceinline__ u16 f2b(float f) {
  __hip_bfloat16 h = __float2bfloat16(f);
  return *reinterpret_cast<u16*>(&h);
}
__device__ __forceinline__ float b2f(u16 u) {
  __hip_bfloat16 h;
  *reinterpret_cast<u16*>(&h) = u;
  return __bfloat162float(h);
}

__device__ __forceinline__ float wave_sum(float v) {
#pragma unroll
  for (int s = 1; s < 64; s <<= 1) v += __shfl_xor(v, s);
  return v;
}
__device__ __forceinline__ float wave_max(float v) {
#pragma unroll
  for (int s = 1; s < 64; s <<= 1) v = fmaxf(v, __shfl_xor(v, s));
  return v;
}

// ---------------- embed: x = emb[idx] * maskb ----------------
__global__ __launch_bounds__(256) void embed_k(const int* __restrict__ idx,
                                               const float* __restrict__ mask,
                                               const float* __restrict__ emb,
                                               float* __restrict__ X) {
  int e = blockIdx.x * 256 + threadIdx.x;
  int mrow = e >> 8, c = e & 255;
  float mb = mask[mrow] > 0.f ? 1.f : 0.f;
  X[e] = emb[idx[mrow] * H_ + c] * mb;
}

// ---------------- dist: masked distances ----------------
__global__ __launch_bounds__(256) void dist_k(const float* __restrict__ pos,
                                              const float* __restrict__ mask,
                                              float* __restrict__ distm) {
  int e = blockIdx.x * 256 + threadIdx.x;
  int j = e % N_;
  int t = e / N_;
  int i = t % N_;
  int b = t / N_;
  float mi = mask[b * N_ + i], mj = mask[b * N_ + j];
  const float* pi = pos + (size_t)(b * N_ + i) * 3;
  const float* pj = pos + (size_t)(b * N_ + j) * 3;
  float dx = pi[0] - pj[0] + 1e-9f;
  float dy = pi[1] - pj[1] + 1e-9f;
  float dz = pi[2] - pj[2] + 1e-9f;
  float d = sqrtf(dx * dx + dy * dy + dz * dz);
  distm[e] = (mi > 0.f && mj > 0.f) ? d : 1e30f;
}

// ---------------- bias table: g_{l,h}(d) ----------------
__global__ __launch_bounds__(256) void table_k(const float* __restrict__ rb_w1,
                                               const float* __restrict__ rb_b1,
                                               const float* __restrict__ rb_w2,
                                               const float* __restrict__ rb_b2,
                                               float* __restrict__ tbl) {
  int bid = blockIdx.x;
  int l = bid / TBL_STRIDE;
  int t = bid % TBL_STRIDE;
  int tid = threadIdx.x;
  float d = (t <= TBL_N) ? (t * (CUT / (float)TBL_N)) : 1.7320508075688772e-9f;
  __shared__ float sf[DD_];
  if (tid < DD_) {
    float ang = PI_ * (tid + 1) * d * (1.f / CUT);
    sf[tid] = sinf(ang) / (d + 1e-6f);
  }
  __syncthreads();
  int h = tid;
  const float* w1 = rb_w1 + (size_t)l * DD_ * H_;
  float pre = rb_b1[l * H_ + h];
#pragma unroll
  for (int k = 0; k < DD_; k++) pre += sf[k] * w1[k * H_ + h];
  float hb = pre / (1.f + expf(-pre));
  const float* w2 = rb_w2 + (size_t)l * H_ * NH_ + h * NH_;
  float part[NH_];
#pragma unroll
  for (int o = 0; o < NH_; o++) part[o] = hb * w2[o];
#pragma unroll
  for (int o = 0; o < NH_; o++) part[o] = wave_sum(part[o]);
  __shared__ float sacc[4][NH_];
  int wave = tid >> 6, lane = tid & 63;
  if (lane == 0) {
#pragma unroll
    for (int o = 0; o < NH_; o++) sacc[wave][o] = part[o];
  }
  __syncthreads();
  if (tid < NH_) {
    float r = sacc[0][tid] + sacc[1][tid] + sacc[2][tid] + sacc[3][tid] + rb_b2[l * NH_ + tid];
    tbl[(size_t)(l * NH_ + tid) * TBL_STRIDE + t] = r;
  }
}

// ---------------- LayerNorm (row of 256) -> bf16 output ----------------
__global__ __launch_bounds__(256) void ln_k(const float* __restrict__ X,
                                            const float* __restrict__ g,
                                            const float* __restrict__ bta,
                                            u16* __restrict__ O) {
  int wave = threadIdx.x >> 6, lane = threadIdx.x & 63;
  int row = blockIdx.x * 4 + wave;
  const float* xr = X + (size_t)row * H_;
  float4 v = *(const float4*)(xr + lane * 4);
  float s = v.x + v.y + v.z + v.w;
  s = wave_sum(s);
  float m = s * (1.f / H_);
  float dx = v.x - m, dy = v.y - m, dz = v.z - m, dw = v.w - m;
  float vs = dx * dx + dy * dy + dz * dz + dw * dw;
  vs = wave_sum(vs);
  float rs = rsqrtf(vs * (1.f / H_) + 1e-5f);
  float4 gg = *(const float4*)(g + lane * 4);
  float4 bb = *(const float4*)(bta + lane * 4);
  u16x4 o;
  o[0] = f2b(dx * rs * gg.x + bb.x);
  o[1] = f2b(dy * rs * gg.y + bb.y);
  o[2] = f2b(dz * rs * gg.z + bb.z);
  o[3] = f2b(dw * rs * gg.w + bb.w);
  *(u16x4*)(O + (size_t)row * H_ + lane * 4) = o;
}

// ---------------- weight transpose+cvt: W[K][N] fp32 -> WT[N][K] bf16 ----------------
// grid: (N/32, K/32, batch)
__global__ __launch_bounds__(256) void tr_k(const float* __restrict__ src,
                                            u16* __restrict__ dst, int K, int N) {
  __shared__ float t[32][33];
  int n0 = blockIdx.x * 32, k0 = blockIdx.y * 32;
  const float* s = src + (size_t)blockIdx.z * K * N;
  u16* d = dst + (size_t)blockIdx.z * K * N;
  int tid = threadIdx.x;
  int r = tid >> 3, c4 = (tid & 7) * 4;
  float4 v = *(const float4*)(s + (size_t)(k0 + r) * N + n0 + c4);
  t[r][c4 + 0] = v.x;
  t[r][c4 + 1] = v.y;
  t[r][c4 + 2] = v.z;
  t[r][c4 + 3] = v.w;
  __syncthreads();
  u16x4 o;
  o[0] = f2b(t[c4 + 0][r]);
  o[1] = f2b(t[c4 + 1][r]);
  o[2] = f2b(t[c4 + 2][r]);
  o[3] = f2b(t[c4 + 3][r]);
  *(u16x4*)(d + (size_t)(n0 + r) * K + k0 + c4) = o;
}

// ---------------- bf16 MFMA GEMM ----------------
// C[M,Nc] = act(A'[M,K] @ W[K,Nc] + bias) (+resid)
// A' = PRE ? bf16(Af32 * sigmoid(G)) : A(bf16). W given as WT[N][K] bf16.
// BM=BN=64, BK=128, 256 threads = 4 waves, each wave a 32x32 sub-tile via
// 2x2 of mfma_f32_16x16x32_bf16. LDS slots (8 bf16 = 16B) XOR-swizzled by row.
template <int ACT, bool RES, bool PRE, bool OBF>
__global__ __launch_bounds__(256) void mgemm_k(const void* __restrict__ Av,
                                               const u16* __restrict__ WT,
                                               const float* __restrict__ bias,
                                               const float* __restrict__ resid,
                                               void* __restrict__ Cv, int K, int Nc,
                                               const float* __restrict__ G) {
  __shared__ u16 As[64 * 128];
  __shared__ u16 Bs[64 * 128];
  const int m0 = blockIdx.y * 64, n0 = blockIdx.x * 64;
  const int tid = threadIdx.x;
  const int wave = tid >> 6, lane = tid & 63;
  const int wr = wave >> 1, wc = wave & 1, lr = lane & 15, lg = lane >> 4;
  f32x4 acc[2][2] = {};
  const int srow = tid >> 2, sp = tid & 3;
  for (int k0 = 0; k0 < K; k0 += 128) {
#pragma unroll
    for (int s4 = 0; s4 < 4; s4++) {
      int s = sp * 4 + s4;
      int phys = s ^ (srow & 15);
      if (PRE) {
        const float* ap = (const float*)Av + (size_t)(m0 + srow) * K + k0 + s * 8;
        const float* gp = G + (size_t)(m0 + srow) * K + k0 + s * 8;
        float4 a0 = *(const float4*)ap;
        float4 a1 = *(const float4*)(ap + 4);
        float4 g0 = *(const float4*)gp;
        float4 g1 = *(const float4*)(gp + 4);
        short8 vv;
        vv[0] = (short)f2b(a0.x / (1.f + __expf(-g0.x)));
        vv[1] = (short)f2b(a0.y / (1.f + __expf(-g0.y)));
        vv[2] = (short)f2b(a0.z / (1.f + __expf(-g0.z)));
        vv[3] = (short)f2b(a0.w / (1.f + __expf(-g0.w)));
        vv[4] = (short)f2b(a1.x / (1.f + __expf(-g1.x)));
        vv[5] = (short)f2b(a1.y / (1.f + __expf(-g1.y)));
        vv[6] = (short)f2b(a1.z / (1.f + __expf(-g1.z)));
        vv[7] = (short)f2b(a1.w / (1.f + __expf(-g1.w)));
        *(short8*)&As[srow * 128 + phys * 8] = vv;
      } else {
        const u16* Ab = (const u16*)Av;
        short8 v = *(const short8*)(Ab + (size_t)(m0 + srow) * K + k0 + s * 8);
        *(short8*)&As[srow * 128 + phys * 8] = v;
      }
      short8 w = *(const short8*)(WT + (size_t)(n0 + srow) * K + k0 + s * 8);
      *(short8*)&Bs[srow * 128 + phys * 8] = w;
    }
    __syncthreads();
#pragma unroll
    for (int kk = 0; kk < 4; kk++) {
      int slot = kk * 4 + lg;
      short8 af[2], bf_[2];
#pragma unroll
      for (int i = 0; i < 2; i++) {
        int row = wr * 32 + i * 16 + lr;
        af[i] = *(const short8*)&As[row * 128 + (slot ^ (row & 15)) * 8];
      }
#pragma unroll
      for (int j = 0; j < 2; j++) {
        int row = wc * 32 + j * 16 + lr;
        bf_[j] = *(const short8*)&Bs[row * 128 + (slot ^ (row & 15)) * 8];
      }
#pragma unroll
      for (int i = 0; i < 2; i++)
#pragma unroll
        for (int j = 0; j < 2; j++)
          acc[i][j] = __builtin_amdgcn_mfma_f32_16x16x32_bf16(af[i], bf_[j], acc[i][j], 0, 0, 0);
    }
    __syncthreads();
  }
#pragma unroll
  for (int i = 0; i < 2; i++)
#pragma unroll
    for (int j = 0; j < 2; j++)
#pragma unroll
      for (int rg = 0; rg < 4; rg++) {
        int row = m0 + wr * 32 + i * 16 + lg * 4 + rg;
        int col = n0 + wc * 32 + j * 16 + lr;
        float v = acc[i][j][rg] + bias[col];
        if (ACT == 1) v = v / (1.f + __expf(-v));
        if (ACT == 2) v = 0.5f * v * (1.f + erff(v * 0.70710678118654752f));
        if (RES) v += resid[(size_t)row * Nc + col];
        if (OBF)
          ((u16*)Cv)[(size_t)row * Nc + col] = f2b(v);
        else
          ((float*)Cv)[(size_t)row * Nc + col] = v;
      }
}

// ---------------- fused attention (flash-style, bf16 qkv input, LDS-staged K/V) ----
// grid = B*NH*(N/8); 4 waves; wave handles 2 query rows, lane = key in 64-tile.
// Output epilogue: shfl-fold 64->32 lanes, LDS transpose red[4][32][33],
// 256-thread parallel sum (replaces 64 serial wave_sums).
__global__ __launch_bounds__(256) void attn_k(const u16* __restrict__ qkv,
                                              const float* __restrict__ distm,
                                              const float* __restrict__ tbl_l,
                                              float* __restrict__ ctx) {
  int bid = blockIdx.x;
  int it = bid % (N_ / 8);
  int t2 = bid / (N_ / 8);
  int hh = t2 % NH_;
  int b = t2 / NH_;
  int i0 = it * 8;
  __shared__ float Qs[8][32];
  __shared__ float Ks[64][32];
  __shared__ float Vs[64][32];
  __shared__ float red[4][32][33];
  int tid = threadIdx.x;
  const size_t bb = (size_t)b * N_;
  {
    int r = tid >> 5, k = tid & 31;
    Qs[r][k] = b2f(qkv[(bb + i0 + r) * 768 + hh * 32 + k]);
  }
  int wave = tid >> 6, lane = tid & 63;
  int ra = wave * 2;
  const float* tblh = tbl_l + (size_t)hh * TBL_STRIDE;
  float pc[2][32];
  float mm[2], ll[2];
#pragma unroll
  for (int r = 0; r < 2; r++) {
    mm[r] = NEGV;
    ll[r] = 0.f;
#pragma unroll
    for (int k = 0; k < 32; k++) pc[r][k] = 0.f;
  }
  // staging: row r0 = tid>>2 (all 64 rows), chunk q8 = tid&3 (8 bf16 = 16B)
  const int r0 = tid >> 2, q8 = tid & 3;
  const u16* kbase = qkv + 256 + hh * 32;
  short8 sk, sv;
  sk = *(const short8*)(kbase + (bb + r0) * 768 + q8 * 8);
  sv = *(const short8*)(kbase + 256 + (bb + r0) * 768 + q8 * 8);
  for (int jt = 0; jt < 6; jt++) {
    __syncthreads();
    {
      int s0 = ((2 * q8) ^ (r0 & 7)) * 4, s1 = ((2 * q8 + 1) ^ (r0 & 7)) * 4;
      float4 f0, f1;
      f0.x = b2f((u16)sk[0]); f0.y = b2f((u16)sk[1]); f0.z = b2f((u16)sk[2]); f0.w = b2f((u16)sk[3]);
      f1.x = b2f((u16)sk[4]); f1.y = b2f((u16)sk[5]); f1.z = b2f((u16)sk[6]); f1.w = b2f((u16)sk[7]);
      *(float4*)&Ks[r0][s0] = f0;
      *(float4*)&Ks[r0][s1] = f1;
      f0.x = b2f((u16)sv[0]); f0.y = b2f((u16)sv[1]); f0.z = b2f((u16)sv[2]); f0.w = b2f((u16)sv[3]);
      f1.x = b2f((u16)sv[4]); f1.y = b2f((u16)sv[5]); f1.z = b2f((u16)sv[6]); f1.w = b2f((u16)sv[7]);
      *(float4*)&Vs[r0][s0] = f0;
      *(float4*)&Vs[r0][s1] = f1;
    }
    __syncthreads();
    if (jt < 5) {
      sk = *(const short8*)(kbase + (bb + (jt + 1) * 64 + r0) * 768 + q8 * 8);
      sv = *(const short8*)(kbase + 256 + (bb + (jt + 1) * 64 + r0) * 768 + q8 * 8);
    }
    float Kr[32], Vr[32];
    const int lsw = lane & 7;
#pragma unroll
    for (int q = 0; q < 8; q++) {
      *(float4*)&Kr[q * 4] = *(const float4*)&Ks[lane][(q ^ lsw) << 2];
      *(float4*)&Vr[q * 4] = *(const float4*)&Vs[lane][(q ^ lsw) << 2];
    }
    int j = jt * 64 + lane;
#pragma unroll
    for (int r = 0; r < 2; r++) {
      int irow = i0 + ra + r;
      float d = distm[(bb + irow) * N_ + j];
      float lg = 0.f;
      const float4* qp = (const float4*)Qs[ra + r];
#pragma unroll
      for (int q = 0; q < 8; q++) {
        float4 qq = qp[q];
        lg += qq.x * Kr[q * 4] + qq.y * Kr[q * 4 + 1] + qq.z * Kr[q * 4 + 2] + qq.w * Kr[q * 4 + 3];
      }
      lg *= INVSC;
      if (d <= CUT) {
        float u = d * ((float)TBL_N / CUT);
        int ix = (int)u;
        ix = ix > TBL_N - 1 ? TBL_N - 1 : ix;
        float fr = u - (float)ix;
        float bias = (j == irow) ? tblh[TBL_N + 1]
                                 : (tblh[ix] * (1.f - fr) + tblh[ix + 1] * fr);
        lg += bias;
      } else {
        lg = NEGV;
      }
      float mt = wave_max(lg);
      float mn = fmaxf(mm[r], mt);
      float al = __expf(mm[r] - mn);
      float p = __expf(lg - mn);
      ll[r] = ll[r] * al + p;
#pragma unroll
      for (int k = 0; k < 32; k++) pc[r][k] = pc[r][k] * al + p * Vr[k];
      mm[r] = mn;
    }
  }
  // epilogue: parallel cross-lane reduction
  float Ls[2];
  Ls[0] = wave_sum(ll[0]);
  Ls[1] = wave_sum(ll[1]);
  int cc = tid >> 1;
  int kout = cc & 31, hf = tid & 1;
#pragma unroll
  for (int r = 0; r < 2; r++) {
    __syncthreads();
#pragma unroll
    for (int k = 0; k < 32; k++) {
      float v = pc[r][k] + __shfl_xor(pc[r][k], 32);
      if (lane < 32) red[wave][k][lane] = v;
    }
    __syncthreads();
    float s = 0.f;
#pragma unroll
    for (int u = 0; u < 16; u++) s += red[wave][kout][hf * 16 + u];
    s += __shfl_xor(s, 1);
    if (hf == 0) {
      int row = i0 + wave * 2 + r;
      ctx[(bb + row) * H_ + hh * 32 + kout] = s / Ls[r];
    }
  }
}

// ---------------- energy: masked mean over nodes then dot with eh_w ----------------
__global__ __launch_bounds__(256) void energy_k(const float* __restrict__ p2,
                                                const float* __restrict__ mask,
                                                const float* __restrict__ ehw,
                                                const float* __restrict__ ehb,
                                                float* __restrict__ out) {
  int b = blockIdx.x, h = threadIdx.x;
  float s = 0.f, cnt = 0.f;
  for (int i = 0; i < N_; i++) {
    float m = mask[b * N_ + i] > 0.f ? 1.f : 0.f;
    s += p2[(size_t)(b * N_ + i) * H_ + h] * m;
    cnt += m;
  }
  float val = s * ehw[h];
  __shared__ float red[256];
  red[h] = val;
  __syncthreads();
  for (int st = 128; st > 0; st >>= 1) {
    if (h < st) red[h] += red[h + st];
    __syncthreads();
  }
  if (h == 0) {
    float c = cnt < 1.f ? 1.f : cnt;
    out[b] = red[0] / c + ehb[0];
  }
}

extern "C" void kernel_launch(void* const* d_in, const int* in_sizes, int n_in,
                              void* d_out, int out_size, void* d_ws, size_t ws_size,
                              hipStream_t stream) {
  const int* node_idx = (const int*)d_in[0];
  const float* positions = (const float*)d_in[1];
  const float* mask = (const float*)d_in[2];
  const float* emb = (const float*)d_in[3];
  const float* ln1_g = (const float*)d_in[4];
  const float* ln1_b = (const float*)d_in[5];
  const float* qkv_w = (const float*)d_in[6];
  const float* qkv_b = (const float*)d_in[7];
  const float* out_w = (const float*)d_in[8];
  const float* out_b = (const float*)d_in[9];
  const float* rb_w1 = (const float*)d_in[10];
  const float* rb_b1 = (const float*)d_in[11];
  const float* rb_w2 = (const float*)d_in[12];
  const float* rb_b2 = (const float*)d_in[13];
  const float* gate_w1 = (const float*)d_in[14];
  const float* gate_b1 = (const float*)d_in[15];
  const float* gate_w2 = (const float*)d_in[16];
  const float* gate_b2 = (const float*)d_in[17];
  const float* ln2_g = (const float*)d_in[18];
  const float* ln2_b = (const float*)d_in[19];
  const float* ff_w1 = (const float*)d_in[20];
  const float* ff_b1 = (const float*)d_in[21];
  const float* ff_w2 = (const float*)d_in[22];
  const float* ff_b2 = (const float*)d_in[23];
  const float* pool_g = (const float*)d_in[24];
  const float* pool_beta = (const float*)d_in[25];
  const float* pool_w = (const float*)d_in[26];
  const float* pool_b = (const float*)d_in[27];
  const float* eh_w = (const float*)d_in[28];
  const float* eh_b = (const float*)d_in[29];
  float* eout = (float*)d_out;

  // workspace layout (bytes)
  char* W8 = (char*)d_ws;
  float* x = (float*)(W8 + 0);              // 1572864 B
  u16* qkvb = (u16*)(W8 + 1572864);         // 2359296 B  (M x 768 bf16)
  float* ctx = (float*)(W8 + 3932160);      // 1572864 B
  float* g2 = (float*)(W8 + 5505024);       // 1572864 B
  u16* hb = (u16*)(W8 + 7077888);           // 786432 B   (M x H bf16)
  u16* g1b = (u16*)(W8 + 7864320);          // 786432 B
  u16* ffb = (u16*)(W8 + 8650752);          // 1572864 B  (M x 512 bf16)
  float* distm = (float*)(W8 + 10223616);   // 2359296 B
  float* tbl = (float*)(W8 + 12582912);     // 524544 B
  u16* wt = (u16*)(W8 + 13107456);          // 5373952 B total
  u16* wt_qkv = wt;                 // 4*768*256
  u16* wt_out = wt + 786432;        // 4*256*256
  u16* wt_g1 = wt + 1048576;
  u16* wt_g2 = wt + 1310720;
  u16* wt_f1 = wt + 1572864;        // 4*512*256
  u16* wt_f2 = wt + 2097152;        // 4*256*512 -> [N=256][K=512]
  u16* wt_p = wt + 2621440;         // 256*256

  // ---- setup ----
  embed_k<<<M_ * H_ / 256, 256, 0, stream>>>(node_idx, mask, emb, x);
  dist_k<<<B_ * N_ * N_ / 256, 256, 0, stream>>>(positions, mask, distm);
  table_k<<<L_ * TBL_STRIDE, 256, 0, stream>>>(rb_w1, rb_b1, rb_w2, rb_b2, tbl);
  tr_k<<<dim3(24, 8, 4), 256, 0, stream>>>(qkv_w, wt_qkv, 256, 768);
  tr_k<<<dim3(8, 8, 4), 256, 0, stream>>>(out_w, wt_out, 256, 256);
  tr_k<<<dim3(8, 8, 4), 256, 0, stream>>>(gate_w1, wt_g1, 256, 256);
  tr_k<<<dim3(8, 8, 4), 256, 0, stream>>>(gate_w2, wt_g2, 256, 256);
  tr_k<<<dim3(16, 8, 4), 256, 0, stream>>>(ff_w1, wt_f1, 256, 512);
  tr_k<<<dim3(8, 16, 4), 256, 0, stream>>>(ff_w2, wt_f2, 512, 256);
  tr_k<<<dim3(8, 8, 1), 256, 0, stream>>>(pool_w, wt_p, 256, 256);

  for (int l = 0; l < L_; l++) {
    const float* qb = qkv_b + (size_t)l * 3 * H_;
    const float* ob = out_b + (size_t)l * H_;
    const float* gb1 = gate_b1 + (size_t)l * H_;
    const float* gb2 = gate_b2 + (size_t)l * H_;
    const float* fb1 = ff_b1 + (size_t)l * 2 * H_;
    const float* fb2 = ff_b2 + (size_t)l * H_;
    u16* wq = wt_qkv + (size_t)l * 768 * 256;
    u16* wo = wt_out + (size_t)l * 256 * 256;
    u16* wg1 = wt_g1 + (size_t)l * 256 * 256;
    u16* wg2 = wt_g2 + (size_t)l * 256 * 256;
    u16* wf1 = wt_f1 + (size_t)l * 512 * 256;
    u16* wf2 = wt_f2 + (size_t)l * 256 * 512;

    // hb = bf16(LN1(x))
    ln_k<<<M_ / 4, 256, 0, stream>>>(x, ln1_g + l * H_, ln1_b + l * H_, hb);
    // qkvb = hb @ qkv_w + qkv_b (bf16 out)
    mgemm_k<0, false, false, true><<<dim3(12, 24), 256, 0, stream>>>(
        hb, wq, qb, nullptr, qkvb, 256, 768, nullptr);
    // ctx = attention(qkvb, dist, bias-table)
    attn_k<<<B_ * NH_ * (N_ / 8), 256, 0, stream>>>(qkvb, distm,
                                                    tbl + (size_t)l * NH_ * TBL_STRIDE, ctx);
    // g1b = bf16(silu(hb @ gate_w1 + gate_b1))
    mgemm_k<1, false, false, true><<<dim3(4, 24), 256, 0, stream>>>(
        hb, wg1, gb1, nullptr, g1b, 256, 256, nullptr);
    // g2 = g1b @ gate_w2 + gate_b2 (fp32 out)
    mgemm_k<0, false, false, false><<<dim3(4, 24), 256, 0, stream>>>(
        g1b, wg2, gb2, nullptr, g2, 256, 256, nullptr);
    // x = x + bf16(ctx * sigmoid(g2)) @ out_w + out_b
    mgemm_k<0, true, true, false><<<dim3(4, 24), 256, 0, stream>>>(
        ctx, wo, ob, x, x, 256, 256, g2);
    // g1b = bf16(LN2(x))
    ln_k<<<M_ / 4, 256, 0, stream>>>(x, ln2_g + l * H_, ln2_b + l * H_, g1b);
    // ffb = bf16(gelu(g1b @ ff_w1 + ff_b1))
    mgemm_k<2, false, false, true><<<dim3(8, 24), 256, 0, stream>>>(
        g1b, wf1, fb1, nullptr, ffb, 256, 512, nullptr);
    // x = x + ffb @ ff_w2 + ff_b2
    mgemm_k<0, true, false, false><<<dim3(4, 24), 256, 0, stream>>>(
        ffb, wf2, fb2, x, x, 512, 256, nullptr);
  }

  // pooling head
  ln_k<<<M_ / 4, 256, 0, stream>>>(x, pool_g, pool_beta, hb);
  mgemm_k<1, false, false, false><<<dim3(4, 24), 256, 0, stream>>>(
      hb, wt_p, pool_b, nullptr, ctx, 256, 256, nullptr);
  energy_k<<<B_, 256, 0, stream>>>(ctx, mask, eh_w, eh_b, eout);
}

// Round 6
// 437.205 us; speedup vs baseline: 3.8712x; 1.4583x over previous
//
#include <hip/hip_runtime.h>
#include <hip/hip_bf16.h>
#include <math.h>

// Problem constants (hardcoded from reference)
constexpr int B_ = 4, N_ = 384, H_ = 256, NH_ = 8, DD_ = 32, L_ = 4;
constexpr int M_ = B_ * N_;          // 1536 node rows
constexpr float CUT = 5.0f;
constexpr float PI_ = 3.14159265358979323846f;
constexpr float INVSC = 0.17677669529663687f;  // 1/sqrt(32)
constexpr int TBL_N = 4096;
constexpr int TBL_STRIDE = 4098;
constexpr float NEGV = -3.0e38f;

typedef __attribute__((ext_vector_type(8))) short short8;
typedef __attribute__((ext_vector_type(4))) float f32x4;
typedef __attribute__((ext_vector_type(4))) unsigned short u16x4;
using u16 = unsigned short;

__device__ __forceinline__ u16 f2b(float f) {
  __hip_bfloat16 h = __float2bfloat16(f);
  return *reinterpret_cast<u16*>(&h);
}
__device__ __forceinline__ float b2f(u16 u) {
  __hip_bfloat16 h;
  *reinterpret_cast<u16*>(&h) = u;
  return __bfloat162float(h);
}
__device__ __forceinline__ void cvt8(float* o, short8 v) {
#pragma unroll
  for (int i = 0; i < 8; i++) o[i] = b2f((u16)v[i]);
}

__device__ __forceinline__ float wave_sum(float v) {
#pragma unroll
  for (int s = 1; s < 64; s <<= 1) v += __shfl_xor(v, s);
  return v;
}
__device__ __forceinline__ float wave_max(float v) {
#pragma unroll
  for (int s = 1; s < 64; s <<= 1) v = fmaxf(v, __shfl_xor(v, s));
  return v;
}

// ---------------- embed: x = emb[idx] * maskb ----------------
__global__ __launch_bounds__(256) void embed_k(const int* __restrict__ idx,
                                               const float* __restrict__ mask,
                                               const float* __restrict__ emb,
                                               float* __restrict__ X) {
  int e = blockIdx.x * 256 + threadIdx.x;
  int mrow = e >> 8, c = e & 255;
  float mb = mask[mrow] > 0.f ? 1.f : 0.f;
  X[e] = emb[idx[mrow] * H_ + c] * mb;
}

// ---------------- dist: masked distances ----------------
__global__ __launch_bounds__(256) void dist_k(const float* __restrict__ pos,
                                              const float* __restrict__ mask,
                                              float* __restrict__ distm) {
  int e = blockIdx.x * 256 + threadIdx.x;
  int j = e % N_;
  int t = e / N_;
  int i = t % N_;
  int b = t / N_;
  float mi = mask[b * N_ + i], mj = mask[b * N_ + j];
  const float* pi = pos + (size_t)(b * N_ + i) * 3;
  const float* pj = pos + (size_t)(b * N_ + j) * 3;
  float dx = pi[0] - pj[0] + 1e-9f;
  float dy = pi[1] - pj[1] + 1e-9f;
  float dz = pi[2] - pj[2] + 1e-9f;
  float d = sqrtf(dx * dx + dy * dy + dz * dz);
  distm[e] = (mi > 0.f && mj > 0.f) ? d : 1e30f;
}

// ---------------- bias table: g_{l,h}(d) ----------------
__global__ __launch_bounds__(256) void table_k(const float* __restrict__ rb_w1,
                                               const float* __restrict__ rb_b1,
                                               const float* __restrict__ rb_w2,
                                               const float* __restrict__ rb_b2,
                                               float* __restrict__ tbl) {
  int bid = blockIdx.x;
  int l = bid / TBL_STRIDE;
  int t = bid % TBL_STRIDE;
  int tid = threadIdx.x;
  float d = (t <= TBL_N) ? (t * (CUT / (float)TBL_N)) : 1.7320508075688772e-9f;
  __shared__ float sf[DD_];
  if (tid < DD_) {
    float ang = PI_ * (tid + 1) * d * (1.f / CUT);
    sf[tid] = sinf(ang) / (d + 1e-6f);
  }
  __syncthreads();
  int h = tid;
  const float* w1 = rb_w1 + (size_t)l * DD_ * H_;
  float pre = rb_b1[l * H_ + h];
#pragma unroll
  for (int k = 0; k < DD_; k++) pre += sf[k] * w1[k * H_ + h];
  float hb = pre / (1.f + expf(-pre));
  const float* w2 = rb_w2 + (size_t)l * H_ * NH_ + h * NH_;
  float part[NH_];
#pragma unroll
  for (int o = 0; o < NH_; o++) part[o] = hb * w2[o];
#pragma unroll
  for (int o = 0; o < NH_; o++) part[o] = wave_sum(part[o]);
  __shared__ float sacc[4][NH_];
  int wave = tid >> 6, lane = tid & 63;
  if (lane == 0) {
#pragma unroll
    for (int o = 0; o < NH_; o++) sacc[wave][o] = part[o];
  }
  __syncthreads();
  if (tid < NH_) {
    float r = sacc[0][tid] + sacc[1][tid] + sacc[2][tid] + sacc[3][tid] + rb_b2[l * NH_ + tid];
    tbl[(size_t)(l * NH_ + tid) * TBL_STRIDE + t] = r;
  }
}

// ---------------- per-layer bias tensor: biasb[b][h][i][j] bf16 (mask folded) ----
// grid dim3(N*N/256, NH, B); massively parallel -> gather latency hidden by TLP.
__global__ __launch_bounds__(256) void bias_k(const float* __restrict__ distm,
                                              const float* __restrict__ tbl_l,
                                              u16* __restrict__ biasb) {
  int h = blockIdx.y, bz = blockIdx.z;
  int e = blockIdx.x * 256 + threadIdx.x;  // < N*N
  int i = e / N_, j = e - i * N_;
  float d = distm[((size_t)bz * N_ + i) * N_ + j];
  const float* tblh = tbl_l + (size_t)h * TBL_STRIDE;
  u16 out;
  if (d <= CUT) {
    float v;
    if (i == j) {
      v = tblh[TBL_N + 1];
    } else {
      float u = d * ((float)TBL_N / CUT);
      int ix = (int)u;
      ix = ix > TBL_N - 1 ? TBL_N - 1 : ix;
      float fr = u - (float)ix;
      v = tblh[ix] * (1.f - fr) + tblh[ix + 1] * fr;
    }
    out = f2b(v);
  } else {
    out = 0xFF80;  // -inf in bf16
  }
  biasb[(((size_t)(bz * NH_ + h)) * N_ + i) * N_ + j] = out;
}

// ---------------- LayerNorm (row of 256) -> bf16 output ----------------
__global__ __launch_bounds__(256) void ln_k(const float* __restrict__ X,
                                            const float* __restrict__ g,
                                            const float* __restrict__ bta,
                                            u16* __restrict__ O) {
  int wave = threadIdx.x >> 6, lane = threadIdx.x & 63;
  int row = blockIdx.x * 4 + wave;
  const float* xr = X + (size_t)row * H_;
  float4 v = *(const float4*)(xr + lane * 4);
  float s = v.x + v.y + v.z + v.w;
  s = wave_sum(s);
  float m = s * (1.f / H_);
  float dx = v.x - m, dy = v.y - m, dz = v.z - m, dw = v.w - m;
  float vs = dx * dx + dy * dy + dz * dz + dw * dw;
  vs = wave_sum(vs);
  float rs = rsqrtf(vs * (1.f / H_) + 1e-5f);
  float4 gg = *(const float4*)(g + lane * 4);
  float4 bb = *(const float4*)(bta + lane * 4);
  u16x4 o;
  o[0] = f2b(dx * rs * gg.x + bb.x);
  o[1] = f2b(dy * rs * gg.y + bb.y);
  o[2] = f2b(dz * rs * gg.z + bb.z);
  o[3] = f2b(dw * rs * gg.w + bb.w);
  *(u16x4*)(O + (size_t)row * H_ + lane * 4) = o;
}

// ---------------- weight transpose+cvt: W[K][N] fp32 -> WT[N][K] bf16 ----------------
__global__ __launch_bounds__(256) void tr_k(const float* __restrict__ src,
                                            u16* __restrict__ dst, int K, int N) {
  __shared__ float t[32][33];
  int n0 = blockIdx.x * 32, k0 = blockIdx.y * 32;
  const float* s = src + (size_t)blockIdx.z * K * N;
  u16* d = dst + (size_t)blockIdx.z * K * N;
  int tid = threadIdx.x;
  int r = tid >> 3, c4 = (tid & 7) * 4;
  float4 v = *(const float4*)(s + (size_t)(k0 + r) * N + n0 + c4);
  t[r][c4 + 0] = v.x;
  t[r][c4 + 1] = v.y;
  t[r][c4 + 2] = v.z;
  t[r][c4 + 3] = v.w;
  __syncthreads();
  u16x4 o;
  o[0] = f2b(t[c4 + 0][r]);
  o[1] = f2b(t[c4 + 1][r]);
  o[2] = f2b(t[c4 + 2][r]);
  o[3] = f2b(t[c4 + 3][r]);
  *(u16x4*)(d + (size_t)(n0 + r) * K + k0 + c4) = o;
}

// ---------------- bf16 MFMA GEMM ----------------
template <int ACT, bool RES, bool PRE, bool OBF>
__global__ __launch_bounds__(256) void mgemm_k(const void* __restrict__ Av,
                                               const u16* __restrict__ WT,
                                               const float* __restrict__ bias,
                                               const float* __restrict__ resid,
                                               void* __restrict__ Cv, int K, int Nc,
                                               const float* __restrict__ G) {
  __shared__ u16 As[64 * 128];
  __shared__ u16 Bs[64 * 128];
  const int m0 = blockIdx.y * 64, n0 = blockIdx.x * 64;
  const int tid = threadIdx.x;
  const int wave = tid >> 6, lane = tid & 63;
  const int wr = wave >> 1, wc = wave & 1, lr = lane & 15, lg = lane >> 4;
  f32x4 acc[2][2] = {};
  const int srow = tid >> 2, sp = tid & 3;
  for (int k0 = 0; k0 < K; k0 += 128) {
#pragma unroll
    for (int s4 = 0; s4 < 4; s4++) {
      int s = sp * 4 + s4;
      int phys = s ^ (srow & 15);
      if (PRE) {
        const float* ap = (const float*)Av + (size_t)(m0 + srow) * K + k0 + s * 8;
        const float* gp = G + (size_t)(m0 + srow) * K + k0 + s * 8;
        float4 a0 = *(const float4*)ap;
        float4 a1 = *(const float4*)(ap + 4);
        float4 g0 = *(const float4*)gp;
        float4 g1 = *(const float4*)(gp + 4);
        short8 vv;
        vv[0] = (short)f2b(a0.x / (1.f + __expf(-g0.x)));
        vv[1] = (short)f2b(a0.y / (1.f + __expf(-g0.y)));
        vv[2] = (short)f2b(a0.z / (1.f + __expf(-g0.z)));
        vv[3] = (short)f2b(a0.w / (1.f + __expf(-g0.w)));
        vv[4] = (short)f2b(a1.x / (1.f + __expf(-g1.x)));
        vv[5] = (short)f2b(a1.y / (1.f + __expf(-g1.y)));
        vv[6] = (short)f2b(a1.z / (1.f + __expf(-g1.z)));
        vv[7] = (short)f2b(a1.w / (1.f + __expf(-g1.w)));
        *(short8*)&As[srow * 128 + phys * 8] = vv;
      } else {
        const u16* Ab = (const u16*)Av;
        short8 v = *(const short8*)(Ab + (size_t)(m0 + srow) * K + k0 + s * 8);
        *(short8*)&As[srow * 128 + phys * 8] = v;
      }
      short8 w = *(const short8*)(WT + (size_t)(n0 + srow) * K + k0 + s * 8);
      *(short8*)&Bs[srow * 128 + phys * 8] = w;
    }
    __syncthreads();
#pragma unroll
    for (int kk = 0; kk < 4; kk++) {
      int slot = kk * 4 + lg;
      short8 af[2], bf_[2];
#pragma unroll
      for (int i = 0; i < 2; i++) {
        int row = wr * 32 + i * 16 + lr;
        af[i] = *(const short8*)&As[row * 128 + (slot ^ (row & 15)) * 8];
      }
#pragma unroll
      for (int j = 0; j < 2; j++) {
        int row = wc * 32 + j * 16 + lr;
        bf_[j] = *(const short8*)&Bs[row * 128 + (slot ^ (row & 15)) * 8];
      }
#pragma unroll
      for (int i = 0; i < 2; i++)
#pragma unroll
        for (int j = 0; j < 2; j++)
          acc[i][j] = __builtin_amdgcn_mfma_f32_16x16x32_bf16(af[i], bf_[j], acc[i][j], 0, 0, 0);
    }
    __syncthreads();
  }
#pragma unroll
  for (int i = 0; i < 2; i++)
#pragma unroll
    for (int j = 0; j < 2; j++)
#pragma unroll
      for (int rg = 0; rg < 4; rg++) {
        int row = m0 + wr * 32 + i * 16 + lg * 4 + rg;
        int col = n0 + wc * 32 + j * 16 + lr;
        float v = acc[i][j][rg] + bias[col];
        if (ACT == 1) v = v / (1.f + __expf(-v));
        if (ACT == 2) v = 0.5f * v * (1.f + erff(v * 0.70710678118654752f));
        if (RES) v += resid[(size_t)row * Nc + col];
        if (OBF)
          ((u16*)Cv)[(size_t)row * Nc + col] = f2b(v);
        else
          ((float*)Cv)[(size_t)row * Nc + col] = v;
      }
}

// ---------------- fused attention v3: full-row softmax, precomputed bias ----------
// grid = B*NH*(N/16); 512 threads = 8 waves; wave handles 2 query rows.
// Whole K/V [384][32] staged in LDS as bf16 (chunk-XOR swizzle -> b128 floor).
// Logits for a full row held in 6 regs -> ONE wave_max/wave_sum per row
// (vs 6 online-softmax chains); bias/mask is one coalesced bf16 load.
__global__ __launch_bounds__(512) void attn_k(const u16* __restrict__ qkv,
                                              const u16* __restrict__ biasb,
                                              float* __restrict__ ctx) {
  int bid = blockIdx.x;
  int it = bid % (N_ / 16);
  int t2 = bid / (N_ / 16);
  int hh = t2 % NH_;
  int b = t2 / NH_;
  int i0 = it * 16;
  __shared__ u16 Ks[384 * 32];
  __shared__ u16 Vs[384 * 32];
  __shared__ float Qs[16][32];
  __shared__ float red[8][32][36];
  int tid = threadIdx.x;
  const size_t bb = (size_t)b * N_;
  // stage Q (f32)
  if (tid < 128) {
    int r = tid >> 3, c4 = (tid & 7) * 4;
    u16x4 q4 = *(const u16x4*)(qkv + (bb + i0 + r) * 768 + hh * 32 + c4);
    Qs[r][c4 + 0] = b2f(q4[0]);
    Qs[r][c4 + 1] = b2f(q4[1]);
    Qs[r][c4 + 2] = b2f(q4[2]);
    Qs[r][c4 + 3] = b2f(q4[3]);
  }
  // stage all K/V rows (bf16, swizzled: phys chunk = c ^ ((row>>1)&3))
#pragma unroll
  for (int m = 0; m < 3; m++) {
    int idx = m * 512 + tid;  // < 1536
    int row = idx >> 2, c = idx & 3;
    int phys = c ^ ((row >> 1) & 3);
    const u16* kb = qkv + (bb + row) * 768 + 256 + hh * 32 + c * 8;
    *(short8*)&Ks[row * 32 + phys * 8] = *(const short8*)kb;
    *(short8*)&Vs[row * 32 + phys * 8] = *(const short8*)(kb + 256);
  }
  __syncthreads();
  int wave = tid >> 6, lane = tid & 63;
  int ra = wave * 2;
  const u16* bptr = biasb + (size_t)(b * NH_ + hh) * N_ * N_;
  const int sw = (lane >> 1) & 3;
  float lg[2][6];
  // ---- QK pass ----
  for (int t = 0; t < 6; t++) {
    int j = t * 64 + lane;
    float Kr[32];
#pragma unroll
    for (int c = 0; c < 4; c++) cvt8(&Kr[c * 8], *(const short8*)&Ks[j * 32 + (c ^ sw) * 8]);
#pragma unroll
    for (int r = 0; r < 2; r++) {
      int irow = i0 + ra + r;
      float acc = 0.f;
      const float4* qp = (const float4*)Qs[ra + r];
#pragma unroll
      for (int q = 0; q < 8; q++) {
        float4 qq = qp[q];
        acc += qq.x * Kr[q * 4] + qq.y * Kr[q * 4 + 1] + qq.z * Kr[q * 4 + 2] + qq.w * Kr[q * 4 + 3];
      }
      float bv = b2f(bptr[(size_t)irow * N_ + j]);
      lg[r][t] = acc * INVSC + bv;
    }
  }
  // ---- softmax (exact, full row) ----
  float Ls[2];
#pragma unroll
  for (int r = 0; r < 2; r++) {
    float mx = lg[r][0];
#pragma unroll
    for (int t = 1; t < 6; t++) mx = fmaxf(mx, lg[r][t]);
    mx = wave_max(mx);
    float s = 0.f;
#pragma unroll
    for (int t = 0; t < 6; t++) {
      lg[r][t] = __expf(lg[r][t] - mx);  // reuse as p
      s += lg[r][t];
    }
    Ls[r] = wave_sum(s);
  }
  // ---- PV pass ----
  float pc[2][32];
#pragma unroll
  for (int r = 0; r < 2; r++)
#pragma unroll
    for (int k = 0; k < 32; k++) pc[r][k] = 0.f;
  for (int t = 0; t < 6; t++) {
    int j = t * 64 + lane;
    float Vr[32];
#pragma unroll
    for (int c = 0; c < 4; c++) cvt8(&Vr[c * 8], *(const short8*)&Vs[j * 32 + (c ^ sw) * 8]);
#pragma unroll
    for (int r = 0; r < 2; r++)
#pragma unroll
      for (int k = 0; k < 32; k++) pc[r][k] += lg[r][t] * Vr[k];
  }
  // ---- epilogue: fold 64->32, LDS transpose, parallel sum ----
  int kout = lane >> 1, hf = lane & 1;
#pragma unroll
  for (int r = 0; r < 2; r++) {
    __syncthreads();
#pragma unroll
    for (int k = 0; k < 32; k++) {
      float v = pc[r][k] + __shfl_xor(pc[r][k], 32);
      if (lane < 32) red[wave][k][lane] = v;
    }
    __syncthreads();
    float s = 0.f;
#pragma unroll
    for (int u = 0; u < 4; u++) {
      float4 q4 = *(const float4*)&red[wave][kout][hf * 16 + u * 4];
      s += q4.x + q4.y + q4.z + q4.w;
    }
    s += __shfl_xor(s, 1);
    if (hf == 0) {
      int row = i0 + ra + r;
      ctx[(bb + row) * H_ + hh * 32 + kout] = s / Ls[r];
    }
  }
}

// ---------------- energy: masked mean over nodes then dot with eh_w ----------------
__global__ __launch_bounds__(256) void energy_k(const float* __restrict__ p2,
                                                const float* __restrict__ mask,
                                                const float* __restrict__ ehw,
                                                const float* __restrict__ ehb,
                                                float* __restrict__ out) {
  int b = blockIdx.x, h = threadIdx.x;
  float s = 0.f, cnt = 0.f;
  for (int i = 0; i < N_; i++) {
    float m = mask[b * N_ + i] > 0.f ? 1.f : 0.f;
    s += p2[(size_t)(b * N_ + i) * H_ + h] * m;
    cnt += m;
  }
  float val = s * ehw[h];
  __shared__ float red[256];
  red[h] = val;
  __syncthreads();
  for (int st = 128; st > 0; st >>= 1) {
    if (h < st) red[h] += red[h + st];
    __syncthreads();
  }
  if (h == 0) {
    float c = cnt < 1.f ? 1.f : cnt;
    out[b] = red[0] / c + ehb[0];
  }
}

extern "C" void kernel_launch(void* const* d_in, const int* in_sizes, int n_in,
                              void* d_out, int out_size, void* d_ws, size_t ws_size,
                              hipStream_t stream) {
  const int* node_idx = (const int*)d_in[0];
  const float* positions = (const float*)d_in[1];
  const float* mask = (const float*)d_in[2];
  const float* emb = (const float*)d_in[3];
  const float* ln1_g = (const float*)d_in[4];
  const float* ln1_b = (const float*)d_in[5];
  const float* qkv_w = (const float*)d_in[6];
  const float* qkv_b = (const float*)d_in[7];
  const float* out_w = (const float*)d_in[8];
  const float* out_b = (const float*)d_in[9];
  const float* rb_w1 = (const float*)d_in[10];
  const float* rb_b1 = (const float*)d_in[11];
  const float* rb_w2 = (const float*)d_in[12];
  const float* rb_b2 = (const float*)d_in[13];
  const float* gate_w1 = (const float*)d_in[14];
  const float* gate_b1 = (const float*)d_in[15];
  const float* gate_w2 = (const float*)d_in[16];
  const float* gate_b2 = (const float*)d_in[17];
  const float* ln2_g = (const float*)d_in[18];
  const float* ln2_b = (const float*)d_in[19];
  const float* ff_w1 = (const float*)d_in[20];
  const float* ff_b1 = (const float*)d_in[21];
  const float* ff_w2 = (const float*)d_in[22];
  const float* ff_b2 = (const float*)d_in[23];
  const float* pool_g = (const float*)d_in[24];
  const float* pool_beta = (const float*)d_in[25];
  const float* pool_w = (const float*)d_in[26];
  const float* pool_b = (const float*)d_in[27];
  const float* eh_w = (const float*)d_in[28];
  const float* eh_b = (const float*)d_in[29];
  float* eout = (float*)d_out;

  // workspace layout (bytes)
  char* W8 = (char*)d_ws;
  float* x = (float*)(W8 + 0);              // 1572864 B
  u16* qkvb = (u16*)(W8 + 1572864);         // 2359296 B  (M x 768 bf16)
  float* ctx = (float*)(W8 + 3932160);      // 1572864 B
  float* g2 = (float*)(W8 + 5505024);       // 1572864 B
  u16* hb = (u16*)(W8 + 7077888);           // 786432 B   (M x H bf16)
  u16* g1b = (u16*)(W8 + 7864320);          // 786432 B
  u16* ffb = (u16*)(W8 + 8650752);          // 1572864 B  (M x 512 bf16)
  float* distm = (float*)(W8 + 10223616);   // 2359296 B
  float* tbl = (float*)(W8 + 12582912);     // 524544 B
  u16* wt = (u16*)(W8 + 13107456);          // 5373952 B
  u16* wt_qkv = wt;                 // 4*768*256
  u16* wt_out = wt + 786432;        // 4*256*256
  u16* wt_g1 = wt + 1048576;
  u16* wt_g2 = wt + 1310720;
  u16* wt_f1 = wt + 1572864;        // 4*512*256
  u16* wt_f2 = wt + 2097152;        // 4*256*512 -> [N=256][K=512]
  u16* wt_p = wt + 2621440;         // 256*256
  u16* biasb = (u16*)(W8 + 18481408);       // 9437184 B (B*NH*N*N bf16), per-layer reuse

  // ---- setup ----
  embed_k<<<M_ * H_ / 256, 256, 0, stream>>>(node_idx, mask, emb, x);
  dist_k<<<B_ * N_ * N_ / 256, 256, 0, stream>>>(positions, mask, distm);
  table_k<<<L_ * TBL_STRIDE, 256, 0, stream>>>(rb_w1, rb_b1, rb_w2, rb_b2, tbl);
  tr_k<<<dim3(24, 8, 4), 256, 0, stream>>>(qkv_w, wt_qkv, 256, 768);
  tr_k<<<dim3(8, 8, 4), 256, 0, stream>>>(out_w, wt_out, 256, 256);
  tr_k<<<dim3(8, 8, 4), 256, 0, stream>>>(gate_w1, wt_g1, 256, 256);
  tr_k<<<dim3(8, 8, 4), 256, 0, stream>>>(gate_w2, wt_g2, 256, 256);
  tr_k<<<dim3(16, 8, 4), 256, 0, stream>>>(ff_w1, wt_f1, 256, 512);
  tr_k<<<dim3(8, 16, 4), 256, 0, stream>>>(ff_w2, wt_f2, 512, 256);
  tr_k<<<dim3(8, 8, 1), 256, 0, stream>>>(pool_w, wt_p, 256, 256);

  for (int l = 0; l < L_; l++) {
    const float* qb = qkv_b + (size_t)l * 3 * H_;
    const float* ob = out_b + (size_t)l * H_;
    const float* gb1 = gate_b1 + (size_t)l * H_;
    const float* gb2 = gate_b2 + (size_t)l * H_;
    const float* fb1 = ff_b1 + (size_t)l * 2 * H_;
    const float* fb2 = ff_b2 + (size_t)l * H_;
    u16* wq = wt_qkv + (size_t)l * 768 * 256;
    u16* wo = wt_out + (size_t)l * 256 * 256;
    u16* wg1 = wt_g1 + (size_t)l * 256 * 256;
    u16* wg2 = wt_g2 + (size_t)l * 256 * 256;
    u16* wf1 = wt_f1 + (size_t)l * 512 * 256;
    u16* wf2 = wt_f2 + (size_t)l * 256 * 512;

    // biasb = masked bias tensor for this layer
    bias_k<<<dim3(N_ * N_ / 256, NH_, B_), 256, 0, stream>>>(
        distm, tbl + (size_t)l * NH_ * TBL_STRIDE, biasb);
    // hb = bf16(LN1(x))
    ln_k<<<M_ / 4, 256, 0, stream>>>(x, ln1_g + l * H_, ln1_b + l * H_, hb);
    // qkvb = hb @ qkv_w + qkv_b (bf16 out)
    mgemm_k<0, false, false, true><<<dim3(12, 24), 256, 0, stream>>>(
        hb, wq, qb, nullptr, qkvb, 256, 768, nullptr);
    // ctx = attention(qkvb, biasb)
    attn_k<<<B_ * NH_ * (N_ / 16), 512, 0, stream>>>(qkvb, biasb, ctx);
    // g1b = bf16(silu(hb @ gate_w1 + gate_b1))
    mgemm_k<1, false, false, true><<<dim3(4, 24), 256, 0, stream>>>(
        hb, wg1, gb1, nullptr, g1b, 256, 256, nullptr);
    // g2 = g1b @ gate_w2 + gate_b2 (fp32 out)
    mgemm_k<0, false, false, false><<<dim3(4, 24), 256, 0, stream>>>(
        g1b, wg2, gb2, nullptr, g2, 256, 256, nullptr);
    // x = x + bf16(ctx * sigmoid(g2)) @ out_w + out_b
    mgemm_k<0, true, true, false><<<dim3(4, 24), 256, 0, stream>>>(
        ctx, wo, ob, x, x, 256, 256, g2);
    // g1b = bf16(LN2(x))
    ln_k<<<M_ / 4, 256, 0, stream>>>(x, ln2_g + l * H_, ln2_b + l * H_, g1b);
    // ffb = bf16(gelu(g1b @ ff_w1 + ff_b1))
    mgemm_k<2, false, false, true><<<dim3(8, 24), 256, 0, stream>>>(
        g1b, wf1, fb1, nullptr, ffb, 256, 512, nullptr);
    // x = x + ffb @ ff_w2 + ff_b2
    mgemm_k<0, true, false, false><<<dim3(4, 24), 256, 0, stream>>>(
        ffb, wf2, fb2, x, x, 512, 256, nullptr);
  }

  // pooling head
  ln_k<<<M_ / 4, 256, 0, stream>>>(x, pool_g, pool_beta, hb);
  mgemm_k<1, false, false, false><<<dim3(4, 24), 256, 0, stream>>>(
      hb, wt_p, pool_b, nullptr, ctx, 256, 256, nullptr);
  energy_k<<<B_, 256, 0, stream>>>(ctx, mask, eh_w, eh_b, eout);
}

// Round 7
// 403.640 us; speedup vs baseline: 4.1931x; 1.0832x over previous
//
#include <hip/hip_runtime.h>
#include <hip/hip_bf16.h>
#include <math.h>

// Problem constants (hardcoded from reference)
constexpr int B_ = 4, N_ = 384, H_ = 256, NH_ = 8, DD_ = 32, L_ = 4;
constexpr int M_ = B_ * N_;          // 1536 node rows
constexpr float CUT = 5.0f;
constexpr float PI_ = 3.14159265358979323846f;
constexpr float INVSC = 0.17677669529663687f;  // 1/sqrt(32)
constexpr int TBL_N = 4096;
constexpr int TBL_STRIDE = 4098;

typedef __attribute__((ext_vector_type(8))) short short8;
typedef __attribute__((ext_vector_type(4))) float f32x4;
typedef __attribute__((ext_vector_type(4))) unsigned short u16x4;
using u16 = unsigned short;

__device__ __forceinline__ u16 f2b(float f) {
  __hip_bfloat16 h = __float2bfloat16(f);
  return *reinterpret_cast<u16*>(&h);
}
__device__ __forceinline__ float b2f(u16 u) {
  __hip_bfloat16 h;
  *reinterpret_cast<u16*>(&h) = u;
  return __bfloat162float(h);
}
__device__ __forceinline__ void cvt8(float* o, short8 v) {
#pragma unroll
  for (int i = 0; i < 8; i++) o[i] = b2f((u16)v[i]);
}

__device__ __forceinline__ float wave_sum(float v) {
#pragma unroll
  for (int s = 1; s < 64; s <<= 1) v += __shfl_xor(v, s);
  return v;
}
__device__ __forceinline__ float wave_max(float v) {
#pragma unroll
  for (int s = 1; s < 64; s <<= 1) v = fmaxf(v, __shfl_xor(v, s));
  return v;
}

// ---------------- embed: x = emb[idx] * maskb ----------------
__global__ __launch_bounds__(256) void embed_k(const int* __restrict__ idx,
                                               const float* __restrict__ mask,
                                               const float* __restrict__ emb,
                                               float* __restrict__ X) {
  int e = blockIdx.x * 256 + threadIdx.x;
  int mrow = e >> 8, c = e & 255;
  float mb = mask[mrow] > 0.f ? 1.f : 0.f;
  X[e] = emb[idx[mrow] * H_ + c] * mb;
}

// ---------------- dist: masked distances ----------------
__global__ __launch_bounds__(256) void dist_k(const float* __restrict__ pos,
                                              const float* __restrict__ mask,
                                              float* __restrict__ distm) {
  int e = blockIdx.x * 256 + threadIdx.x;
  int j = e % N_;
  int t = e / N_;
  int i = t % N_;
  int b = t / N_;
  float mi = mask[b * N_ + i], mj = mask[b * N_ + j];
  const float* pi = pos + (size_t)(b * N_ + i) * 3;
  const float* pj = pos + (size_t)(b * N_ + j) * 3;
  float dx = pi[0] - pj[0] + 1e-9f;
  float dy = pi[1] - pj[1] + 1e-9f;
  float dz = pi[2] - pj[2] + 1e-9f;
  float d = sqrtf(dx * dx + dy * dy + dz * dz);
  distm[e] = (mi > 0.f && mj > 0.f) ? d : 1e30f;
}

// ---------------- bias table v2: block computes 64 t-entries, all heads ---------
// grid dim3(65, L_), 256 threads.
// Phase A: 2048 features -> LDS (all lanes sinf-busy).
// Phase B1: thread h holds w1 column in regs, computes hb[64][256] -> padded LDS.
// Phase B2: 512 outputs = direct dots over LDS rows (broadcast, conflict-free).
__global__ __launch_bounds__(256) void table_k(const float* __restrict__ rb_w1,
                                               const float* __restrict__ rb_b1,
                                               const float* __restrict__ rb_w2,
                                               const float* __restrict__ rb_b2,
                                               float* __restrict__ tbl) {
  constexpr int TT = 64;
  int l = blockIdx.y;
  int t0 = blockIdx.x * TT;
  int tid = threadIdx.x;
  __shared__ float sfA[TT][32];
  __shared__ float hbA[TT][260];  // pad 260: B2 reads spread over 8 banks
#pragma unroll
  for (int m = 0; m < 8; m++) {
    int idx = m * 256 + tid;  // < 2048
    int tl = idx >> 5, k = idx & 31;
    int t = t0 + tl;
    float d = (t <= TBL_N) ? (t * (CUT / (float)TBL_N)) : 1.7320508075688772e-9f;
    float ang = PI_ * (k + 1) * d * (1.f / CUT);
    sfA[tl][k] = sinf(ang) / (d + 1e-6f);
  }
  __syncthreads();
  // B1: h = tid
  float w1c[32];
  const float* w1 = rb_w1 + (size_t)l * DD_ * H_;
#pragma unroll
  for (int k = 0; k < 32; k++) w1c[k] = w1[k * H_ + tid];
  float b1v = rb_b1[l * H_ + tid];
  for (int tl = 0; tl < TT; tl++) {
    float pre = b1v;
    const float4* sfp = (const float4*)sfA[tl];
#pragma unroll
    for (int kq = 0; kq < 8; kq++) {
      float4 s4 = sfp[kq];
      pre += s4.x * w1c[kq * 4] + s4.y * w1c[kq * 4 + 1] + s4.z * w1c[kq * 4 + 2] +
             s4.w * w1c[kq * 4 + 3];
    }
    hbA[tl][tid] = pre / (1.f + __expf(-pre));
  }
  __syncthreads();
  // B2: thread -> (o = tid&7), two t values
  const float* w2 = rb_w2 + (size_t)l * H_ * NH_;
  int o = tid & 7;
  float b2v = rb_b2[l * NH_ + o];
#pragma unroll
  for (int half = 0; half < 2; half++) {
    int tl = (tid >> 3) + half * 32;
    float acc = b2v;
    const float4* hp = (const float4*)hbA[tl];
#pragma unroll 4
    for (int hq = 0; hq < 64; hq++) {
      float4 h4 = hp[hq];
      acc += h4.x * w2[(hq * 4 + 0) * NH_ + o] + h4.y * w2[(hq * 4 + 1) * NH_ + o] +
             h4.z * w2[(hq * 4 + 2) * NH_ + o] + h4.w * w2[(hq * 4 + 3) * NH_ + o];
    }
    int t = t0 + tl;
    if (t < TBL_STRIDE) tbl[(size_t)(l * NH_ + o) * TBL_STRIDE + t] = acc;
  }
}

// ---------------- per-layer bias tensor, one pass over (b,i,j), all 8 heads ----
__global__ __launch_bounds__(256) void bias_k(const float* __restrict__ distm,
                                              const float* __restrict__ tbl_l,
                                              u16* __restrict__ biasb) {
  int e = blockIdx.x * 256 + threadIdx.x;  // < B*N*N
  int j = e % N_;
  int t = e / N_;
  int i = t % N_;
  int b = t / N_;
  float d = distm[e];
  size_t obase = ((size_t)b * NH_) * N_ * N_ + (size_t)i * N_ + j;
  if (d <= CUT) {
    float u = d * ((float)TBL_N / CUT);
    int ix = (int)u;
    ix = ix > TBL_N - 1 ? TBL_N - 1 : ix;
    float fr = u - (float)ix;
    bool diag = (i == j);
#pragma unroll
    for (int h = 0; h < NH_; h++) {
      const float* tblh = tbl_l + (size_t)h * TBL_STRIDE;
      float v = diag ? tblh[TBL_N + 1] : (tblh[ix] * (1.f - fr) + tblh[ix + 1] * fr);
      biasb[obase + (size_t)h * N_ * N_] = f2b(v);
    }
  } else {
#pragma unroll
    for (int h = 0; h < NH_; h++) biasb[obase + (size_t)h * N_ * N_] = 0xFF80;  // -inf
  }
}

// ---------------- LayerNorm (row of 256) -> bf16 output ----------------
__global__ __launch_bounds__(256) void ln_k(const float* __restrict__ X,
                                            const float* __restrict__ g,
                                            const float* __restrict__ bta,
                                            u16* __restrict__ O) {
  int wave = threadIdx.x >> 6, lane = threadIdx.x & 63;
  int row = blockIdx.x * 4 + wave;
  const float* xr = X + (size_t)row * H_;
  float4 v = *(const float4*)(xr + lane * 4);
  float s = v.x + v.y + v.z + v.w;
  s = wave_sum(s);
  float m = s * (1.f / H_);
  float dx = v.x - m, dy = v.y - m, dz = v.z - m, dw = v.w - m;
  float vs = dx * dx + dy * dy + dz * dz + dw * dw;
  vs = wave_sum(vs);
  float rs = rsqrtf(vs * (1.f / H_) + 1e-5f);
  float4 gg = *(const float4*)(g + lane * 4);
  float4 bb = *(const float4*)(bta + lane * 4);
  u16x4 o;
  o[0] = f2b(dx * rs * gg.x + bb.x);
  o[1] = f2b(dy * rs * gg.y + bb.y);
  o[2] = f2b(dz * rs * gg.z + bb.z);
  o[3] = f2b(dw * rs * gg.w + bb.w);
  *(u16x4*)(O + (size_t)row * H_ + lane * 4) = o;
}

// ---------------- weight transpose+cvt: W[K][N] fp32 -> WT[N][K] bf16 ----------------
// dstride = per-z element stride of dst (allows packing into combined buffers)
__global__ __launch_bounds__(256) void tr_k(const float* __restrict__ src,
                                            u16* __restrict__ dst, int K, int N,
                                            int dstride) {
  __shared__ float t[32][33];
  int n0 = blockIdx.x * 32, k0 = blockIdx.y * 32;
  const float* s = src + (size_t)blockIdx.z * K * N;
  u16* d = dst + (size_t)blockIdx.z * dstride;
  int tid = threadIdx.x;
  int r = tid >> 3, c4 = (tid & 7) * 4;
  float4 v = *(const float4*)(s + (size_t)(k0 + r) * N + n0 + c4);
  t[r][c4 + 0] = v.x;
  t[r][c4 + 1] = v.y;
  t[r][c4 + 2] = v.z;
  t[r][c4 + 3] = v.w;
  __syncthreads();
  u16x4 o;
  o[0] = f2b(t[c4 + 0][r]);
  o[1] = f2b(t[c4 + 1][r]);
  o[2] = f2b(t[c4 + 2][r]);
  o[3] = f2b(t[c4 + 3][r]);
  *(u16x4*)(d + (size_t)(n0 + r) * K + k0 + c4) = o;
}

// ---------------- bf16 MFMA GEMM ----------------
// C[M,Nc] = act(A'[M,K] @ W[K,Nc] + bias) (+resid)
// ACT: 0 none, 1 silu, 2 gelu, 3 = none for col<768 (bias), silu for col>=768 (bias2)
// A row stride = lda elements. W given as WT[N][K] bf16.
template <int ACT, bool RES, bool PRE, bool OBF>
__global__ __launch_bounds__(256) void mgemm_k(const void* __restrict__ Av,
                                               const u16* __restrict__ WT,
                                               const float* __restrict__ bias,
                                               const float* __restrict__ resid,
                                               void* __restrict__ Cv, int K, int Nc,
                                               int lda, const float* __restrict__ G,
                                               const float* __restrict__ bias2) {
  __shared__ u16 As[64 * 128];
  __shared__ u16 Bs[64 * 128];
  const int m0 = blockIdx.y * 64, n0 = blockIdx.x * 64;
  const int tid = threadIdx.x;
  const int wave = tid >> 6, lane = tid & 63;
  const int wr = wave >> 1, wc = wave & 1, lr = lane & 15, lg = lane >> 4;
  f32x4 acc[2][2] = {};
  const int srow = tid >> 2, sp = tid & 3;
  for (int k0 = 0; k0 < K; k0 += 128) {
#pragma unroll
    for (int s4 = 0; s4 < 4; s4++) {
      int s = sp * 4 + s4;
      int phys = s ^ (srow & 15);
      if (PRE) {
        const float* ap = (const float*)Av + (size_t)(m0 + srow) * lda + k0 + s * 8;
        const float* gp = G + (size_t)(m0 + srow) * lda + k0 + s * 8;
        float4 a0 = *(const float4*)ap;
        float4 a1 = *(const float4*)(ap + 4);
        float4 g0 = *(const float4*)gp;
        float4 g1 = *(const float4*)(gp + 4);
        short8 vv;
        vv[0] = (short)f2b(a0.x / (1.f + __expf(-g0.x)));
        vv[1] = (short)f2b(a0.y / (1.f + __expf(-g0.y)));
        vv[2] = (short)f2b(a0.z / (1.f + __expf(-g0.z)));
        vv[3] = (short)f2b(a0.w / (1.f + __expf(-g0.w)));
        vv[4] = (short)f2b(a1.x / (1.f + __expf(-g1.x)));
        vv[5] = (short)f2b(a1.y / (1.f + __expf(-g1.y)));
        vv[6] = (short)f2b(a1.z / (1.f + __expf(-g1.z)));
        vv[7] = (short)f2b(a1.w / (1.f + __expf(-g1.w)));
        *(short8*)&As[srow * 128 + phys * 8] = vv;
      } else {
        const u16* Ab = (const u16*)Av;
        short8 v = *(const short8*)(Ab + (size_t)(m0 + srow) * lda + k0 + s * 8);
        *(short8*)&As[srow * 128 + phys * 8] = v;
      }
      short8 w = *(const short8*)(WT + (size_t)(n0 + srow) * K + k0 + s * 8);
      *(short8*)&Bs[srow * 128 + phys * 8] = w;
    }
    __syncthreads();
#pragma unroll
    for (int kk = 0; kk < 4; kk++) {
      int slot = kk * 4 + lg;
      short8 af[2], bf_[2];
#pragma unroll
      for (int i = 0; i < 2; i++) {
        int row = wr * 32 + i * 16 + lr;
        af[i] = *(const short8*)&As[row * 128 + (slot ^ (row & 15)) * 8];
      }
#pragma unroll
      for (int j = 0; j < 2; j++) {
        int row = wc * 32 + j * 16 + lr;
        bf_[j] = *(const short8*)&Bs[row * 128 + (slot ^ (row & 15)) * 8];
      }
#pragma unroll
      for (int i = 0; i < 2; i++)
#pragma unroll
        for (int j = 0; j < 2; j++)
          acc[i][j] = __builtin_amdgcn_mfma_f32_16x16x32_bf16(af[i], bf_[j], acc[i][j], 0, 0, 0);
    }
    __syncthreads();
  }
#pragma unroll
  for (int i = 0; i < 2; i++)
#pragma unroll
    for (int j = 0; j < 2; j++)
#pragma unroll
      for (int rg = 0; rg < 4; rg++) {
        int row = m0 + wr * 32 + i * 16 + lg * 4 + rg;
        int col = n0 + wc * 32 + j * 16 + lr;
        float v;
        if (ACT == 3) {
          float bv = (col < 768) ? bias[col] : bias2[col - 768];
          v = acc[i][j][rg] + bv;
          if (col >= 768) v = v / (1.f + __expf(-v));
        } else {
          v = acc[i][j][rg] + bias[col];
          if (ACT == 1) v = v / (1.f + __expf(-v));
          if (ACT == 2) v = 0.5f * v * (1.f + erff(v * 0.70710678118654752f));
        }
        if (RES) v += resid[(size_t)row * Nc + col];
        if (OBF)
          ((u16*)Cv)[(size_t)row * Nc + col] = f2b(v);
        else
          ((float*)Cv)[(size_t)row * Nc + col] = v;
      }
}

// ---------------- fused attention v3: full-row softmax, precomputed bias ----------
// grid = B*NH*(N/16); 512 threads = 8 waves; wave handles 2 query rows.
__global__ __launch_bounds__(512) void attn_k(const u16* __restrict__ qkv,
                                              const u16* __restrict__ biasb,
                                              float* __restrict__ ctx, int qs) {
  int bid = blockIdx.x;
  int it = bid % (N_ / 16);
  int t2 = bid / (N_ / 16);
  int hh = t2 % NH_;
  int b = t2 / NH_;
  int i0 = it * 16;
  __shared__ u16 Ks[384 * 32];
  __shared__ u16 Vs[384 * 32];
  __shared__ float Qs[16][32];
  __shared__ float red[8][32][36];
  int tid = threadIdx.x;
  const size_t bb = (size_t)b * N_;
  if (tid < 128) {
    int r = tid >> 3, c4 = (tid & 7) * 4;
    u16x4 q4 = *(const u16x4*)(qkv + (bb + i0 + r) * qs + hh * 32 + c4);
    Qs[r][c4 + 0] = b2f(q4[0]);
    Qs[r][c4 + 1] = b2f(q4[1]);
    Qs[r][c4 + 2] = b2f(q4[2]);
    Qs[r][c4 + 3] = b2f(q4[3]);
  }
#pragma unroll
  for (int m = 0; m < 3; m++) {
    int idx = m * 512 + tid;  // < 1536
    int row = idx >> 2, c = idx & 3;
    int phys = c ^ ((row >> 1) & 3);
    const u16* kb = qkv + (bb + row) * qs + 256 + hh * 32 + c * 8;
    *(short8*)&Ks[row * 32 + phys * 8] = *(const short8*)kb;
    *(short8*)&Vs[row * 32 + phys * 8] = *(const short8*)(kb + 256);
  }
  __syncthreads();
  int wave = tid >> 6, lane = tid & 63;
  int ra = wave * 2;
  const u16* bptr = biasb + (size_t)(b * NH_ + hh) * N_ * N_;
  const int sw = (lane >> 1) & 3;
  float lg[2][6];
  for (int t = 0; t < 6; t++) {
    int j = t * 64 + lane;
    float Kr[32];
#pragma unroll
    for (int c = 0; c < 4; c++) cvt8(&Kr[c * 8], *(const short8*)&Ks[j * 32 + (c ^ sw) * 8]);
#pragma unroll
    for (int r = 0; r < 2; r++) {
      int irow = i0 + ra + r;
      float acc = 0.f;
      const float4* qp = (const float4*)Qs[ra + r];
#pragma unroll
      for (int q = 0; q < 8; q++) {
        float4 qq = qp[q];
        acc += qq.x * Kr[q * 4] + qq.y * Kr[q * 4 + 1] + qq.z * Kr[q * 4 + 2] + qq.w * Kr[q * 4 + 3];
      }
      float bv = b2f(bptr[(size_t)irow * N_ + j]);
      lg[r][t] = acc * INVSC + bv;
    }
  }
  float Ls[2];
#pragma unroll
  for (int r = 0; r < 2; r++) {
    float mx = lg[r][0];
#pragma unroll
    for (int t = 1; t < 6; t++) mx = fmaxf(mx, lg[r][t]);
    mx = wave_max(mx);
    float s = 0.f;
#pragma unroll
    for (int t = 0; t < 6; t++) {
      lg[r][t] = __expf(lg[r][t] - mx);
      s += lg[r][t];
    }
    Ls[r] = wave_sum(s);
  }
  float pc[2][32];
#pragma unroll
  for (int r = 0; r < 2; r++)
#pragma unroll
    for (int k = 0; k < 32; k++) pc[r][k] = 0.f;
  for (int t = 0; t < 6; t++) {
    int j = t * 64 + lane;
    float Vr[32];
#pragma unroll
    for (int c = 0; c < 4; c++) cvt8(&Vr[c * 8], *(const short8*)&Vs[j * 32 + (c ^ sw) * 8]);
#pragma unroll
    for (int r = 0; r < 2; r++)
#pragma unroll
      for (int k = 0; k < 32; k++) pc[r][k] += lg[r][t] * Vr[k];
  }
  int kout = lane >> 1, hf = lane & 1;
#pragma unroll
  for (int r = 0; r < 2; r++) {
    __syncthreads();
#pragma unroll
    for (int k = 0; k < 32; k++) {
      float v = pc[r][k] + __shfl_xor(pc[r][k], 32);
      if (lane < 32) red[wave][k][lane] = v;
    }
    __syncthreads();
    float s = 0.f;
#pragma unroll
    for (int u = 0; u < 4; u++) {
      float4 q4 = *(const float4*)&red[wave][kout][hf * 16 + u * 4];
      s += q4.x + q4.y + q4.z + q4.w;
    }
    s += __shfl_xor(s, 1);
    if (hf == 0) {
      int row = i0 + ra + r;
      ctx[(bb + row) * H_ + hh * 32 + kout] = s / Ls[r];
    }
  }
}

// ---------------- energy: masked mean over nodes then dot with eh_w ----------------
__global__ __launch_bounds__(256) void energy_k(const float* __restrict__ p2,
                                                const float* __restrict__ mask,
                                                const float* __restrict__ ehw,
                                                const float* __restrict__ ehb,
                                                float* __restrict__ out) {
  int b = blockIdx.x, h = threadIdx.x;
  float s = 0.f, cnt = 0.f;
  for (int i = 0; i < N_; i++) {
    float m = mask[b * N_ + i] > 0.f ? 1.f : 0.f;
    s += p2[(size_t)(b * N_ + i) * H_ + h] * m;
    cnt += m;
  }
  float val = s * ehw[h];
  __shared__ float red[256];
  red[h] = val;
  __syncthreads();
  for (int st = 128; st > 0; st >>= 1) {
    if (h < st) red[h] += red[h + st];
    __syncthreads();
  }
  if (h == 0) {
    float c = cnt < 1.f ? 1.f : cnt;
    out[b] = red[0] / c + ehb[0];
  }
}

extern "C" void kernel_launch(void* const* d_in, const int* in_sizes, int n_in,
                              void* d_out, int out_size, void* d_ws, size_t ws_size,
                              hipStream_t stream) {
  const int* node_idx = (const int*)d_in[0];
  const float* positions = (const float*)d_in[1];
  const float* mask = (const float*)d_in[2];
  const float* emb = (const float*)d_in[3];
  const float* ln1_g = (const float*)d_in[4];
  const float* ln1_b = (const float*)d_in[5];
  const float* qkv_w = (const float*)d_in[6];
  const float* qkv_b = (const float*)d_in[7];
  const float* out_w = (const float*)d_in[8];
  const float* out_b = (const float*)d_in[9];
  const float* rb_w1 = (const float*)d_in[10];
  const float* rb_b1 = (const float*)d_in[11];
  const float* rb_w2 = (const float*)d_in[12];
  const float* rb_b2 = (const float*)d_in[13];
  const float* gate_w1 = (const float*)d_in[14];
  const float* gate_b1 = (const float*)d_in[15];
  const float* gate_w2 = (const float*)d_in[16];
  const float* gate_b2 = (const float*)d_in[17];
  const float* ln2_g = (const float*)d_in[18];
  const float* ln2_b = (const float*)d_in[19];
  const float* ff_w1 = (const float*)d_in[20];
  const float* ff_b1 = (const float*)d_in[21];
  const float* ff_w2 = (const float*)d_in[22];
  const float* ff_b2 = (const float*)d_in[23];
  const float* pool_g = (const float*)d_in[24];
  const float* pool_beta = (const float*)d_in[25];
  const float* pool_w = (const float*)d_in[26];
  const float* pool_b = (const float*)d_in[27];
  const float* eh_w = (const float*)d_in[28];
  const float* eh_b = (const float*)d_in[29];
  float* eout = (float*)d_out;

  // workspace layout (bytes)
  char* W8 = (char*)d_ws;
  float* x = (float*)(W8 + 0);              // 1572864 B (M x 256 f32)
  u16* qgb = (u16*)(W8 + 1572864);          // 3145728 B (M x 1024 bf16: q|k|v|g1)
  float* ctx = (float*)(W8 + 4718592);      // 1572864 B
  float* g2 = (float*)(W8 + 6291456);       // 1572864 B
  u16* hb = (u16*)(W8 + 7864320);           // 786432 B  (M x 256 bf16)
  u16* ffb = (u16*)(W8 + 8650752);          // 1572864 B (M x 512 bf16)
  float* distm = (float*)(W8 + 10223616);   // 2359296 B
  float* tbl = (float*)(W8 + 12582912);     // 524544 B
  u16* wt = (u16*)(W8 + 13107456);          // 5373952 B
  u16* wt_qg = wt;                  // 4 x 1024 x 256 (qkv rows 0..767, g1 rows 768..1023)
  u16* wt_out = wt + 1048576;       // 4 x 256 x 256
  u16* wt_g2 = wt + 1310720;
  u16* wt_f1 = wt + 1572864;        // 4 x 512 x 256
  u16* wt_f2 = wt + 2097152;        // 4 x 256 x 512
  u16* wt_p = wt + 2621440;         // 256 x 256
  u16* biasb = (u16*)(W8 + 18481408);       // 9437184 B (B*NH*N*N bf16), per-layer reuse

  // ---- setup ----
  embed_k<<<M_ * H_ / 256, 256, 0, stream>>>(node_idx, mask, emb, x);
  dist_k<<<B_ * N_ * N_ / 256, 256, 0, stream>>>(positions, mask, distm);
  table_k<<<dim3(65, L_), 256, 0, stream>>>(rb_w1, rb_b1, rb_w2, rb_b2, tbl);
  tr_k<<<dim3(24, 8, 4), 256, 0, stream>>>(qkv_w, wt_qg, 256, 768, 262144);
  tr_k<<<dim3(8, 8, 4), 256, 0, stream>>>(gate_w1, wt_qg + 768 * 256, 256, 256, 262144);
  tr_k<<<dim3(8, 8, 4), 256, 0, stream>>>(out_w, wt_out, 256, 256, 65536);
  tr_k<<<dim3(8, 8, 4), 256, 0, stream>>>(gate_w2, wt_g2, 256, 256, 65536);
  tr_k<<<dim3(16, 8, 4), 256, 0, stream>>>(ff_w1, wt_f1, 256, 512, 131072);
  tr_k<<<dim3(8, 16, 4), 256, 0, stream>>>(ff_w2, wt_f2, 512, 256, 131072);
  tr_k<<<dim3(8, 8, 1), 256, 0, stream>>>(pool_w, wt_p, 256, 256, 65536);

  for (int l = 0; l < L_; l++) {
    const float* qb = qkv_b + (size_t)l * 3 * H_;
    const float* ob = out_b + (size_t)l * H_;
    const float* gb1 = gate_b1 + (size_t)l * H_;
    const float* gb2 = gate_b2 + (size_t)l * H_;
    const float* fb1 = ff_b1 + (size_t)l * 2 * H_;
    const float* fb2 = ff_b2 + (size_t)l * H_;
    u16* wqg = wt_qg + (size_t)l * 1024 * 256;
    u16* wo = wt_out + (size_t)l * 256 * 256;
    u16* wg2 = wt_g2 + (size_t)l * 256 * 256;
    u16* wf1 = wt_f1 + (size_t)l * 512 * 256;
    u16* wf2 = wt_f2 + (size_t)l * 256 * 512;

    // biasb = masked bias tensor for this layer
    bias_k<<<B_ * N_ * N_ / 256, 256, 0, stream>>>(
        distm, tbl + (size_t)l * NH_ * TBL_STRIDE, biasb);
    // hb = bf16(LN1(x))
    ln_k<<<M_ / 4, 256, 0, stream>>>(x, ln1_g + l * H_, ln1_b + l * H_, hb);
    // qgb = hb @ [qkv_w | gate_w1] (+biases, silu on g1 cols) -> bf16
    mgemm_k<3, false, false, true><<<dim3(16, 24), 256, 0, stream>>>(
        hb, wqg, qb, nullptr, qgb, 256, 1024, 256, nullptr, gb1);
    // ctx = attention(qgb, biasb)
    attn_k<<<B_ * NH_ * (N_ / 16), 512, 0, stream>>>(qgb, biasb, ctx, 1024);
    // g2 = g1 @ gate_w2 + gate_b2 (fp32 out); g1 = qgb cols 768..1023
    mgemm_k<0, false, false, false><<<dim3(4, 24), 256, 0, stream>>>(
        (const void*)(qgb + 768), wg2, gb2, nullptr, g2, 256, 256, 1024, nullptr, nullptr);
    // x = x + bf16(ctx * sigmoid(g2)) @ out_w + out_b
    mgemm_k<0, true, true, false><<<dim3(4, 24), 256, 0, stream>>>(
        ctx, wo, ob, x, x, 256, 256, 256, g2, nullptr);
    // hb = bf16(LN2(x))
    ln_k<<<M_ / 4, 256, 0, stream>>>(x, ln2_g + l * H_, ln2_b + l * H_, hb);
    // ffb = bf16(gelu(hb @ ff_w1 + ff_b1))
    mgemm_k<2, false, false, true><<<dim3(8, 24), 256, 0, stream>>>(
        hb, wf1, fb1, nullptr, ffb, 256, 512, 256, nullptr, nullptr);
    // x = x + ffb @ ff_w2 + ff_b2
    mgemm_k<0, true, false, false><<<dim3(4, 24), 256, 0, stream>>>(
        ffb, wf2, fb2, x, x, 512, 256, 512, nullptr, nullptr);
  }

  // pooling head
  ln_k<<<M_ / 4, 256, 0, stream>>>(x, pool_g, pool_beta, hb);
  mgemm_k<1, false, false, false><<<dim3(4, 24), 256, 0, stream>>>(
      hb, wt_p, pool_b, nullptr, ctx, 256, 256, 256, nullptr, nullptr);
  energy_k<<<B_, 256, 0, stream>>>(ctx, mask, eh_w, eh_b, eout);
}